// Round 8
// baseline (1477.162 us; speedup 1.0000x reference)
//
#include <hip/hip_runtime.h>
#include <hip/hip_fp16.h>

#define N_NODES 10000
#define N_EDGES 40000
#define N_GRAPH 64
#define CPS     258             // chunks per slice (256 real + bias/pad, all slices uniform)
#define EPAD    40192           // 157 * 256 padded edge count
#define PSLICE  (EPAD * 64)     // floats per partial slice

typedef _Float16 half8_t  __attribute__((ext_vector_type(8)));
typedef float    floatx16 __attribute__((ext_vector_type(16)));

__device__ __forceinline__ void gload_lds16(const void* g, void* l) {
  __builtin_amdgcn_global_load_lds((const __attribute__((address_space(1))) void*)g,
                                   (__attribute__((address_space(3))) void*)l, 16, 0, 0);
}

// swizzle: 16B-slot permutation within each row's 256B chunk image (row bits 0-2)
__device__ __host__ __forceinline__ int swz(int row) {
  return ((row & 3) << 1) | ((row >> 2) & 1);
}

__device__ __forceinline__ half8_t splat8(_Float16 v) {
  half8_t r = {v, v, v, v, v, v, v, v};
  return r;
}

// ---------------- prep: BC[ks][c][row][128 halves], chunk-major, PRE-SWIZZLED.
// logical B'[o][kk_l] = w2_1[k][i*64+o] (kk_l = k*64+i); slice7 chunk256 = bias rank;
// all other c>=256 chunks are zero pads (so every slice runs a uniform 258 chunks).
__global__ void prep_B(const float* __restrict__ w2, const float* __restrict__ b2,
                       _Float16* __restrict__ BC) {
  int tid = blockIdx.x * 256 + threadIdx.x;
  if (tid >= 8 * CPS * 64) return;
  int ks  = tid / (CPS * 64);
  int rem = tid - ks * (CPS * 64);
  int c = rem >> 6;
  int o = rem & 63;
  _Float16* dst = BC + (size_t)tid * 128;
  if (c > 256 || (c == 256 && ks != 7)) {   // zero pad chunk
    for (int j = 0; j < 128; ++j) dst[j] = (_Float16)0.f;
    return;
  }
  int swo = swz(o);
  int kkbase = ks * 32768 + c * 128;
  for (int sp = 0; sp < 16; ++sp) {         // physical 16B slot
    int kk0 = kkbase + ((sp ^ swo) * 8);    // logical joint-kk of this slot
    #pragma unroll
    for (int j3 = 0; j3 < 8; ++j3) {
      int kk_l = kk0 + j3;
      int k = kk_l >> 6, i = kk_l & 63;
      float v;
      if (k < 4096)       v = w2[k * 4096 + i * 64 + o];
      else if (k == 4096) v = b2[i * 64 + o];
      else                v = 0.f;
      dst[sp * 8 + j3] = (_Float16)v;
    }
  }
}

// ---------------- layer 0: per-edge MLP (in_dim=1) + scatter-sum + degree count
__global__ void layer0_edge(const float* __restrict__ node_ids,
                            const int* __restrict__ ei,
                            const float* __restrict__ ea,
                            const float* __restrict__ w1, const float* __restrict__ b1,
                            const float* __restrict__ w2, const float* __restrict__ b2,
                            float* __restrict__ agg0, float* __restrict__ cnt) {
  __shared__ float w1s[256], b1s[64], w2s[4096], b2s[64], zb[4][64];
  int t = threadIdx.x;
  for (int idx = t; idx < 4096; idx += 256) w2s[idx] = w2[idx];
  if (t < 256) w1s[t] = w1[t];
  if (t < 64) { b1s[t] = b1[t]; b2s[t] = b2[t]; }
  __syncthreads();
  int w = t >> 6, l = t & 63;
  int gw = blockIdx.x * 4 + w;
  int nw = gridDim.x * 4;
  for (int e = gw; e < N_EDGES; e += nw) {
    float a0 = ea[e * 4 + 0], a1 = ea[e * 4 + 1], a2 = ea[e * 4 + 2], a3 = ea[e * 4 + 3];
    float z = a0 * w1s[l] + a1 * w1s[64 + l] + a2 * w1s[128 + l] + a3 * w1s[192 + l] + b1s[l];
    zb[w][l] = fmaxf(z, 0.f);
    asm volatile("s_waitcnt lgkmcnt(0)" ::: "memory");
    __builtin_amdgcn_sched_barrier(0);
    float h = b2s[l];
    #pragma unroll
    for (int k = 0; k < 64; ++k) h += zb[w][k] * w2s[k * 64 + l];
    int src = ei[e], dst = ei[N_EDGES + e];
    float msg = node_ids[src] * h;
    atomicAdd(&agg0[dst * 64 + l], msg);
    if (l == 0) atomicAdd(&cnt[dst], 1.0f);
  }
}

// ---------------- node update 0: x1 = relu(agg0/cnt + node_ids*root0 + bias0); pool counts
__global__ void node0(const float* __restrict__ node_ids, const int* __restrict__ batch,
                      const float* __restrict__ agg0, const float* __restrict__ cnt,
                      const float* __restrict__ root0, const float* __restrict__ bias0,
                      float* __restrict__ x1, float* __restrict__ pcnt) {
  int gid = blockIdx.x * 256 + threadIdx.x;
  if (gid >= N_NODES * 64) return;
  int n = gid >> 6, o = gid & 63;
  float c = fmaxf(cnt[n], 1.f);
  float v = agg0[gid] / c + node_ids[n] * root0[o] + bias0[o];
  x1[gid] = fmaxf(v, 0.f);
  if (o == 0) atomicAdd(&pcnt[batch[n]], 1.0f);
}

// ---------------- layer 1 fused: msg[e,o] = sum_kk (z_e[k]*x_e[i]) * B'[kk,o]
// grid = 157 edge-blocks * 8 K-slices; block = 256 thr = 4 waves.
// Wave: 64 edges (2 tiles of 32) x ALL 64 o (n=2). 3-buffer LDS ring, raw s_barrier,
// counted s_waitcnt vmcnt(4): next-next chunk's DMAs stay in flight across barriers (T3/T4).
template <bool PART>
__launch_bounds__(256, 3)
__global__ void fused_edge_gemm(const int* __restrict__ ei,
                                const float* __restrict__ ea,
                                const float* __restrict__ x1,
                                const float* __restrict__ w1, const float* __restrict__ b1,
                                const _Float16* __restrict__ BC,
                                float* __restrict__ outbuf) {
  __shared__ __attribute__((aligned(16))) _Float16 Bl[3][64 * 128]; // swizzled images
  __shared__ __attribute__((aligned(16))) __half2 w1q[256][4];      // 4 w1 pairs per c
  __shared__ __half2 b1p[256];
  int t = threadIdx.x;
  int ks = blockIdx.x & 7;           // K-slice; blockIdx%8 -> XCD -> slice-per-L2 affinity
  int eb = blockIdx.x >> 3;
  int e0 = eb * 256;
  int w = t >> 6, l = t & 63;
  int half_ = l >> 5;                // A/B fragment k-half
  int lane31 = l & 31;
  int swo = swz(lane31);             // same for lane31 and lane31+32 (bits 0-2 only)

  int kb = ks * 512;                 // real-k base of this slice
  {
    int j = t;
    #pragma unroll
    for (int d = 0; d < 4; ++d) {
      float2 v = *(const float2*)(w1 + d * 4096 + kb + 2 * j);
      w1q[j][d] = __floats2half2_rn(v.x, v.y);
    }
    float2 bv = *(const float2*)(b1 + kb + 2 * j);
    b1p[j] = __floats2half2_rn(bv.x, bv.y);
  }

  // per-lane A data: 2 edge-tiles of 32; lane holds x[row=lane31][q*16 + half_*8 + 0..7]
  half8_t xh8[2][4];
  __half2 eb_bc[2][4];               // broadcast edge attrs (R6 style: VALU-lean z-gen)
  #pragma unroll
  for (int m = 0; m < 2; ++m) {
    int e = e0 + w * 64 + m * 32 + lane31;
    if (e < N_EDGES) {
      int src = ei[e];
      const float* xp = x1 + src * 64 + half_ * 8;
      #pragma unroll
      for (int q = 0; q < 4; ++q) {
        float4 f0 = *(const float4*)(xp + q * 16);
        float4 f1 = *(const float4*)(xp + q * 16 + 4);
        half8_t v;
        v[0] = (_Float16)f0.x; v[1] = (_Float16)f0.y;
        v[2] = (_Float16)f0.z; v[3] = (_Float16)f0.w;
        v[4] = (_Float16)f1.x; v[5] = (_Float16)f1.y;
        v[6] = (_Float16)f1.z; v[7] = (_Float16)f1.w;
        xh8[m][q] = v;
      }
      float4 av = *(const float4*)(ea + e * 4);
      eb_bc[m][0] = __float2half2_rn(av.x); eb_bc[m][1] = __float2half2_rn(av.y);
      eb_bc[m][2] = __float2half2_rn(av.z); eb_bc[m][3] = __float2half2_rn(av.w);
    } else {
      #pragma unroll
      for (int q = 0; q < 4; ++q) xh8[m][q] = splat8((_Float16)0.f);
      #pragma unroll
      for (int d = 0; d < 4; ++d) eb_bc[m][d] = __float2half2_rn(0.f);
    }
  }

  floatx16 acc[2][2];
  #pragma unroll
  for (int m = 0; m < 2; ++m)
    #pragma unroll
    for (int n = 0; n < 2; ++n)
      #pragma unroll
      for (int r = 0; r < 16; ++r) acc[m][n][r] = 0.f;

  // preamble done: certify w1q/b1p before any z-gen (vm/lgkm quiet here -> cheap)
  __syncthreads();

  // addressing
  const char* gp = (const char*)BC + (size_t)ks * (CPS * 16384) + w * 4096 + l * 16;
  char*       sd = (char*)&Bl[0][0] + w * 4096 + l * 16;     // stage dst base (+sb*16384)
  const char* rb = (const char*)&Bl[0][0] + lane31 * 256;    // read base (+rbuf*16384)

  auto stg = [&](int sb) {           // stage next pending chunk into ring buffer sb
    char* d = sd + sb * 16384;
    gload_lds16(gp,        d);
    gload_lds16(gp + 1024, d + 1024);
    gload_lds16(gp + 2048, d + 2048);
    gload_lds16(gp + 3072, d + 3072);
    gp += 16384;
  };

  const __half zero1 = __float2half(0.f);
  union H2F { __half2 h2; _Float16 f[2]; };
  half8_t zs8[2][2];

  auto zgen = [&](int c) {           // z for chunk c's two real k values
    __half2 w0 = w1q[c][0], w1v = w1q[c][1], w2v = w1q[c][2], w3v = w1q[c][3];
    __half2 bv = b1p[c];
    #pragma unroll
    for (int m = 0; m < 2; ++m) {
      __half2 h = __hfma2(eb_bc[m][0], w0, bv);
      h = __hfma2(eb_bc[m][1], w1v, h);
      h = __hfma2(eb_bc[m][2], w2v, h);
      h = __hfma2(eb_bc[m][3], w3v, h);
      H2F u; u.h2 = __halves2half2(__hmax(__low2half(h),  zero1),
                                   __hmax(__high2half(h), zero1));
      zs8[m][0] = splat8(u.f[0]);
      zs8[m][1] = splat8(u.f[1]);
    }
  };
  auto zbias = [&]() {               // slice7 c=256 bias rank; pad chunks have B=0 anyway
    #pragma unroll
    for (int m = 0; m < 2; ++m) {
      zs8[m][0] = splat8((_Float16)1.f);
      zs8[m][1] = splat8((_Float16)0.f);
    }
  };

  auto cmp = [&](int rbuf) {         // 32 MFMA on ring buffer rbuf
    const char* base = rb + rbuf * 16384;
    __builtin_amdgcn_s_setprio(1);
    #pragma unroll
    for (int t8 = 0; t8 < 8; ++t8) {
      int slot = (t8 * 2 + half_) ^ swo;
      const char* ba = base + slot * 16;
      half8_t bf0 = *(const half8_t*)ba;             // o rows 0..31
      half8_t bf1 = *(const half8_t*)(ba + 8192);    // o rows 32..63 (same swizzle)
      #pragma unroll
      for (int m = 0; m < 2; ++m) {
        half8_t af = xh8[m][t8 & 3] * zs8[m][t8 >> 2];
        acc[m][0] = __builtin_amdgcn_mfma_f32_32x32x16_f16(af, bf0, acc[m][0], 0, 0, 0);
        acc[m][1] = __builtin_amdgcn_mfma_f32_32x32x16_f16(af, bf1, acc[m][1], 0, 0, 0);
      }
    }
    __builtin_amdgcn_s_setprio(0);
  };

#define SYNC4 do { asm volatile("s_waitcnt vmcnt(4)" ::: "memory"); \
                   __builtin_amdgcn_sched_barrier(0); \
                   __builtin_amdgcn_s_barrier(); \
                   __builtin_amdgcn_sched_barrier(0); } while (0)
#define SYNC0 do { asm volatile("s_waitcnt vmcnt(0)" ::: "memory"); \
                   __builtin_amdgcn_sched_barrier(0); \
                   __builtin_amdgcn_s_barrier(); \
                   __builtin_amdgcn_sched_barrier(0); } while (0)

  // ring prologue: chunks 0,1 in flight
  stg(0); stg(1);

  // phase c: zgen(c); vmcnt(4) certifies chunk-c loads (FIFO: oldest retire first);
  // barrier; stage c+2 (safe: all waves past reading that buffer); compute on c%3.
  int c = 0;
  for (int it = 0; it < 85; ++it) {  // c = 0..254
    zgen(c);     SYNC4; stg(2); cmp(0);
    zgen(c + 1); SYNC4; stg(0); cmp(1);
    zgen(c + 2); SYNC4; stg(1); cmp(2);
    c += 3;
  }
  // tail: c = 255, 256, 257 (256 = bias/pad rank, 257 = zero pad)
  zgen(255); SYNC4; stg(2); cmp(0);
  zbias();   SYNC4;         cmp(1);   // outstanding = c257's 4 only; c256 already retired
  zbias();   SYNC0;         cmp(2);

#undef SYNC4
#undef SYNC0

  // epilogue: 32x32 C/D layout: col=lane&31, row=(reg&3)+8*(reg>>2)+4*(lane>>5)
  if (PART) {
    float* pb = outbuf + ((size_t)ks * EPAD + e0 + w * 64) * 64 + lane31;
    #pragma unroll
    for (int m = 0; m < 2; ++m) {
      #pragma unroll
      for (int r = 0; r < 16; ++r) {
        int row = m * 32 + (r & 3) + 8 * (r >> 2) + 4 * half_;
        pb[(size_t)row * 64]      = acc[m][0][r];
        pb[(size_t)row * 64 + 32] = acc[m][1][r];
      }
    }
  } else {
    #pragma unroll
    for (int m = 0; m < 2; ++m) {
      #pragma unroll
      for (int r = 0; r < 16; ++r) {
        int e = e0 + w * 64 + m * 32 + (r & 3) + 8 * (r >> 2) + 4 * half_;
        if (e < N_EDGES) {
          int dst = ei[N_EDGES + e];
          atomicAdd(&outbuf[dst * 64 + lane31],      acc[m][0][r]);
          atomicAdd(&outbuf[dst * 64 + lane31 + 32], acc[m][1][r]);
        }
      }
    }
  }
}

// ---------------- reduce 8 partial slices -> scatter into agg1 (8x fewer atomics)
__global__ void reduce_partials(const float* __restrict__ P8, const int* __restrict__ ei,
                                float* __restrict__ agg1) {
  int gid = blockIdx.x * 256 + threadIdx.x;
  if (gid >= N_EDGES * 64) return;
  int e = gid >> 6;
  float s = 0.f;
  #pragma unroll
  for (int ks = 0; ks < 8; ++ks) s += P8[(size_t)ks * PSLICE + gid];
  int dst = ei[N_EDGES + e];
  atomicAdd(&agg1[dst * 64 + (gid & 63)], s);
}

// ---------------- node update 1 + global mean pool accumulate
__global__ void node1_pool(const int* __restrict__ batch, const float* __restrict__ x1,
                           const float* __restrict__ agg1, const float* __restrict__ cnt,
                           const float* __restrict__ root1, const float* __restrict__ bias1,
                           float* __restrict__ psum) {
  __shared__ float rt[4096];
  int t = threadIdx.x;
  for (int idx = t; idx < 4096; idx += 256) rt[idx] = root1[idx];
  __syncthreads();
  int w = t >> 6, l = t & 63;
  int n = blockIdx.x * 4 + w;
  if (n >= N_NODES) return;
  float c = fmaxf(cnt[n], 1.f);
  float acc = agg1[n * 64 + l] / c + bias1[l];
  const float* xp = x1 + n * 64;
  #pragma unroll
  for (int i4 = 0; i4 < 16; ++i4) {
    float4 xv = *(const float4*)(xp + i4 * 4);
    acc += xv.x * rt[(i4 * 4 + 0) * 64 + l] + xv.y * rt[(i4 * 4 + 1) * 64 + l]
         + xv.z * rt[(i4 * 4 + 2) * 64 + l] + xv.w * rt[(i4 * 4 + 3) * 64 + l];
  }
  acc = fmaxf(acc, 0.f);
  atomicAdd(&psum[batch[n] * 64 + l], acc);
}

// ---------------- classifier head: one wave per graph
__global__ void classifier(const float* __restrict__ psum, const float* __restrict__ pcnt,
                           const float* __restrict__ wc1, const float* __restrict__ bc1,
                           const float* __restrict__ wc2, const float* __restrict__ bc2,
                           float* __restrict__ out) {
  __shared__ float hb[64];
  int g = blockIdx.x, j = threadIdx.x;
  float c = fmaxf(pcnt[g], 1.f);
  float h = bc1[j];
  const float* pp = psum + g * 64;
  #pragma unroll
  for (int i4 = 0; i4 < 16; ++i4) {
    float4 pv = *(const float4*)(pp + i4 * 4);
    h += (pv.x / c) * wc1[(i4 * 4 + 0) * 64 + j] + (pv.y / c) * wc1[(i4 * 4 + 1) * 64 + j]
       + (pv.z / c) * wc1[(i4 * 4 + 2) * 64 + j] + (pv.w / c) * wc1[(i4 * 4 + 3) * 64 + j];
  }
  hb[j] = fmaxf(h, 0.f);
  __syncthreads();
  if (j < 4) {
    float o = bc2[j];
    #pragma unroll
    for (int k = 0; k < 64; ++k) o += hb[k] * wc2[k * 4 + j];
    out[g * 4 + j] = o;
  }
}

extern "C" void kernel_launch(void* const* d_in, const int* in_sizes, int n_in,
                              void* d_out, int out_size, void* d_ws, size_t ws_size,
                              hipStream_t stream) {
  const float* node_ids = (const float*)d_in[0];
  const int*   ei       = (const int*)d_in[1];
  const float* ea       = (const float*)d_in[2];
  const int*   batch    = (const int*)d_in[3];
  const float* w1_0 = (const float*)d_in[4];
  const float* b1_0 = (const float*)d_in[5];
  const float* w2_0 = (const float*)d_in[6];
  const float* b2_0 = (const float*)d_in[7];
  const float* root0 = (const float*)d_in[8];
  const float* bias0 = (const float*)d_in[9];
  const float* w1_1 = (const float*)d_in[10];
  const float* b1_1 = (const float*)d_in[11];
  const float* w2_1 = (const float*)d_in[12];
  const float* b2_1 = (const float*)d_in[13];
  const float* root1 = (const float*)d_in[14];
  const float* bias1 = (const float*)d_in[15];
  const float* wc1 = (const float*)d_in[16];
  const float* bc1 = (const float*)d_in[17];
  const float* wc2 = (const float*)d_in[18];
  const float* bc2 = (const float*)d_in[19];
  float* out = (float*)d_out;

  char* ws = (char*)d_ws;
  _Float16* BC = (_Float16*)ws;                        // 33,816,576 B (8*258*16384)
  float* x1   = (float*)(ws + 33816576);               //  2,560,000 B
  float* agg0 = (float*)(ws + 36376576);               //  2,560,000 B (zeroed)
  float* agg1 = (float*)(ws + 38936576);               //  2,560,000 B (zeroed)
  float* cnt  = (float*)(ws + 41496576);               //     40,000 B (zeroed)
  float* psum = (float*)(ws + 41536576);               //     16,384 B (zeroed)
  float* pcnt = (float*)(ws + 41552960);               //        256 B (zeroed)
  float* P8   = (float*)(ws + 41553216);               // 82,313,216 B (fully overwritten)
  const size_t NEED_PART = 41553216ull + (size_t)8 * PSLICE * 4;

  (void)hipMemsetAsync(agg0, 0, 2560000 + 2560000 + 40000 + 16384 + 256, stream);

  prep_B<<<(8 * CPS * 64 + 255) / 256, 256, 0, stream>>>(w2_1, b2_1, BC);
  layer0_edge<<<512, 256, 0, stream>>>(node_ids, ei, ea, w1_0, b1_0, w2_0, b2_0, agg0, cnt);
  node0<<<(N_NODES * 64 + 255) / 256, 256, 0, stream>>>(node_ids, batch, agg0, cnt, root0, bias0, x1, pcnt);

  if (ws_size >= NEED_PART) {
    fused_edge_gemm<true><<<157 * 8, 256, 0, stream>>>(ei, ea, x1, w1_1, b1_1, BC, P8);
    reduce_partials<<<(N_EDGES * 64) / 256, 256, 0, stream>>>(P8, ei, agg1);
  } else {
    fused_edge_gemm<false><<<157 * 8, 256, 0, stream>>>(ei, ea, x1, w1_1, b1_1, BC, agg1);
  }

  node1_pool<<<(N_NODES + 3) / 4, 256, 0, stream>>>(batch, x1, agg1, cnt, root1, bias1, psum);
  classifier<<<N_GRAPH, 64, 0, stream>>>(psum, pcnt, wc1, bc1, wc2, bc2, out);
}

// Round 9
// 1405.533 us; speedup vs baseline: 1.0510x; 1.0510x over previous
//
#include <hip/hip_runtime.h>
#include <hip/hip_fp16.h>

#define N_NODES 10000
#define N_EDGES 40000
#define N_GRAPH 64
#define CPS     257             // chunks per slice (uniform alloc; slices 0-6 use 256)
#define NTILES  1256            // 157 edge-blocks * 8 K-slices
#define NBLOCKS 768             // 256 CU * 3 resident
#define EPAD    40192           // 157 * 256 padded edge count
#define PSLICE  (EPAD * 64)     // floats per partial slice

typedef _Float16 half8_t  __attribute__((ext_vector_type(8)));
typedef float    floatx16 __attribute__((ext_vector_type(16)));

__device__ __forceinline__ void gload_lds16(const void* g, void* l) {
  __builtin_amdgcn_global_load_lds((const __attribute__((address_space(1))) void*)g,
                                   (__attribute__((address_space(3))) void*)l, 16, 0, 0);
}

// swizzle: 16B-slot permutation within each row's 256B chunk image (row bits 0-2)
__device__ __host__ __forceinline__ int swz(int row) {
  return ((row & 3) << 1) | ((row >> 2) & 1);
}

__device__ __forceinline__ half8_t splat8(_Float16 v) {
  half8_t r = {v, v, v, v, v, v, v, v};
  return r;
}

// ---------------- prep: BC[ks][c][row][128 halves], chunk-major, PRE-SWIZZLED
// so a linear global_load_lds DMA lands the bank-conflict-free LDS image.
// logical B'[o][kk_l] = w2_1[k][i*64+o] (kk_l = k*64+i), bias rank at k=4096.
__global__ void prep_B(const float* __restrict__ w2, const float* __restrict__ b2,
                       _Float16* __restrict__ BC) {
  int tid = blockIdx.x * 256 + threadIdx.x;
  if (tid >= 8 * CPS * 64) return;
  int ks  = tid / (CPS * 64);
  int rem = tid - ks * (CPS * 64);
  int c = rem >> 6;
  int o = rem & 63;
  if (c == 256 && ks != 7) return;          // pad chunk, never read
  _Float16* dst = BC + (size_t)tid * 128;
  int swo = swz(o);
  int kkbase = ks * 32768 + c * 128;
  for (int sp = 0; sp < 16; ++sp) {         // physical 16B slot
    int kk0 = kkbase + ((sp ^ swo) * 8);    // logical joint-kk of this slot
    #pragma unroll
    for (int j3 = 0; j3 < 8; ++j3) {
      int kk_l = kk0 + j3;
      int k = kk_l >> 6, i = kk_l & 63;
      float v;
      if (k < 4096)       v = w2[k * 4096 + i * 64 + o];
      else if (k == 4096) v = b2[i * 64 + o];
      else                v = 0.f;
      dst[sp * 8 + j3] = (_Float16)v;
    }
  }
}

// ---------------- layer 0: per-edge MLP (in_dim=1) + scatter-sum + degree count
__global__ void layer0_edge(const float* __restrict__ node_ids,
                            const int* __restrict__ ei,
                            const float* __restrict__ ea,
                            const float* __restrict__ w1, const float* __restrict__ b1,
                            const float* __restrict__ w2, const float* __restrict__ b2,
                            float* __restrict__ agg0, float* __restrict__ cnt) {
  __shared__ float w1s[256], b1s[64], w2s[4096], b2s[64], zb[4][64];
  int t = threadIdx.x;
  for (int idx = t; idx < 4096; idx += 256) w2s[idx] = w2[idx];
  if (t < 256) w1s[t] = w1[t];
  if (t < 64) { b1s[t] = b1[t]; b2s[t] = b2[t]; }
  __syncthreads();
  int w = t >> 6, l = t & 63;
  int gw = blockIdx.x * 4 + w;
  int nw = gridDim.x * 4;
  for (int e = gw; e < N_EDGES; e += nw) {
    float a0 = ea[e * 4 + 0], a1 = ea[e * 4 + 1], a2 = ea[e * 4 + 2], a3 = ea[e * 4 + 3];
    float z = a0 * w1s[l] + a1 * w1s[64 + l] + a2 * w1s[128 + l] + a3 * w1s[192 + l] + b1s[l];
    zb[w][l] = fmaxf(z, 0.f);
    asm volatile("s_waitcnt lgkmcnt(0)" ::: "memory");
    __builtin_amdgcn_sched_barrier(0);
    float h = b2s[l];
    #pragma unroll
    for (int k = 0; k < 64; ++k) h += zb[w][k] * w2s[k * 64 + l];
    int src = ei[e], dst = ei[N_EDGES + e];
    float msg = node_ids[src] * h;
    atomicAdd(&agg0[dst * 64 + l], msg);
    if (l == 0) atomicAdd(&cnt[dst], 1.0f);
  }
}

// ---------------- node update 0: x1 = relu(agg0/cnt + node_ids*root0 + bias0); pool counts
__global__ void node0(const float* __restrict__ node_ids, const int* __restrict__ batch,
                      const float* __restrict__ agg0, const float* __restrict__ cnt,
                      const float* __restrict__ root0, const float* __restrict__ bias0,
                      float* __restrict__ x1, float* __restrict__ pcnt) {
  int gid = blockIdx.x * 256 + threadIdx.x;
  if (gid >= N_NODES * 64) return;
  int n = gid >> 6, o = gid & 63;
  float c = fmaxf(cnt[n], 1.f);
  float v = agg0[gid] / c + node_ids[n] * root0[o] + bias0[o];
  x1[gid] = fmaxf(v, 0.f);
  if (o == 0) atomicAdd(&pcnt[batch[n]], 1.0f);
}

// ---------------- layer 1 fused: msg[e,o] = sum_kk (z_e[k]*x_e[i]) * B'[kk,o]
// PERSISTENT: grid = 768 blocks (256 CU x 3 resident); tiles = 157 eb x 8 ks = 1256,
// first 768 static (tile = blockIdx), rest via atomic queue -> no generation tail.
// Block = 4 waves; wave = 64 edges (2 tiles of 32) x all 64 o (n=2).
template <bool PART>
__launch_bounds__(256, 3)
__global__ void fused_edge_gemm(const int* __restrict__ ei,
                                const float* __restrict__ ea,
                                const float* __restrict__ x1,
                                const float* __restrict__ w1, const float* __restrict__ b1,
                                const _Float16* __restrict__ BC,
                                float* __restrict__ outbuf,
                                int* __restrict__ counter) {
  __shared__ __attribute__((aligned(16))) _Float16 Bl[2][64 * 128]; // swizzled image
  __shared__ __attribute__((aligned(16))) __half2 w1q[256][4];      // 4 w1 pairs per c
  __shared__ __half2 b1p[256];
  __shared__ int nt_sh;
  int t = threadIdx.x;
  int w = t >> 6, l = t & 63;
  int half_ = l >> 5;                // A/B fragment k-half
  int lane31 = l & 31;
  int swo = swz(lane31);             // same for lane31 and lane31+32 (row bits 0-2)

  char* dst0 = (char*)&Bl[0][0] + w * 4096 + l * 16;
  char* dst1 = dst0 + 16384;
  const char* rb = (const char*)&Bl[0][0] + lane31 * 256;

  const __half zero1 = __float2half(0.f);
  union H2F { __half2 h2; _Float16 f[2]; };

  int tile = blockIdx.x;
  while (tile < NTILES) {
    int ks = tile & 7;               // K-slice (first gen: ks == XCD -> L2 affinity)
    int eb = tile >> 3;
    int e0 = eb * 256;
    int kb = ks * 512;               // real-k base of this slice

    // stage w1 slice as packed half2 (prev tile's Bl reads are already fenced
    // by the previous loop's trailing __syncthreads)
    {
      int j = t;
      #pragma unroll
      for (int d = 0; d < 4; ++d) {
        float2 v = *(const float2*)(w1 + d * 4096 + kb + 2 * j);
        w1q[j][d] = __floats2half2_rn(v.x, v.y);
      }
      float2 bv = *(const float2*)(b1 + kb + 2 * j);
      b1p[j] = __floats2half2_rn(bv.x, bv.y);
    }

    // per-lane A data: 2 edge-tiles of 32; lane holds x[row=lane31][q*16+half_*8+0..7]
    half8_t xh8[2][4];
    __half2 eb_bc[2][4];
    #pragma unroll
    for (int m = 0; m < 2; ++m) {
      int e = e0 + w * 64 + m * 32 + lane31;
      if (e < N_EDGES) {
        int src = ei[e];
        const float* xp = x1 + src * 64 + half_ * 8;
        #pragma unroll
        for (int q = 0; q < 4; ++q) {
          float4 f0 = *(const float4*)(xp + q * 16);
          float4 f1 = *(const float4*)(xp + q * 16 + 4);
          half8_t v;
          v[0] = (_Float16)f0.x; v[1] = (_Float16)f0.y;
          v[2] = (_Float16)f0.z; v[3] = (_Float16)f0.w;
          v[4] = (_Float16)f1.x; v[5] = (_Float16)f1.y;
          v[6] = (_Float16)f1.z; v[7] = (_Float16)f1.w;
          xh8[m][q] = v;
        }
        float4 av = *(const float4*)(ea + e * 4);
        eb_bc[m][0] = __float2half2_rn(av.x); eb_bc[m][1] = __float2half2_rn(av.y);
        eb_bc[m][2] = __float2half2_rn(av.z); eb_bc[m][3] = __float2half2_rn(av.w);
      } else {
        #pragma unroll
        for (int q = 0; q < 4; ++q) xh8[m][q] = splat8((_Float16)0.f);
        #pragma unroll
        for (int d = 0; d < 4; ++d) eb_bc[m][d] = __float2half2_rn(0.f);
      }
    }

    floatx16 acc[2][2];
    #pragma unroll
    for (int m = 0; m < 2; ++m)
      #pragma unroll
      for (int n = 0; n < 2; ++n)
        #pragma unroll
        for (int r = 0; r < 16; ++r) acc[m][n][r] = 0.f;

    int nchunk = (ks == 7) ? 257 : 256;
    const char* gp = (const char*)BC + (size_t)ks * (CPS * 16384) + w * 4096 + l * 16;

    auto stage = [&](char* dstb) {   // stage chunk at gp, then advance 16 KB
      gload_lds16(gp,        dstb);
      gload_lds16(gp + 1024, dstb + 1024);
      gload_lds16(gp + 2048, dstb + 2048);
      gload_lds16(gp + 3072, dstb + 3072);
      gp += 16384;
    };

    stage(dst0);
    __syncthreads();                 // w1q ready + chunk0 landed

    int cur = 0;
    for (int c = 0; c < nchunk; ++c) {
      if (c + 1 < nchunk) stage(cur ? dst0 : dst1);   // DMA lands during compute

      half8_t zs8[2][2];
      if (c < 256) {
        __half2 w0 = w1q[c][0], w1v = w1q[c][1], w2v = w1q[c][2], w3v = w1q[c][3];
        __half2 bv = b1p[c];
        #pragma unroll
        for (int m = 0; m < 2; ++m) {
          __half2 h = __hfma2(eb_bc[m][0], w0, bv);
          h = __hfma2(eb_bc[m][1], w1v, h);
          h = __hfma2(eb_bc[m][2], w2v, h);
          h = __hfma2(eb_bc[m][3], w3v, h);
          H2F u; u.h2 = __halves2half2(__hmax(__low2half(h),  zero1),
                                       __hmax(__high2half(h), zero1));
          zs8[m][0] = splat8(u.f[0]);
          zs8[m][1] = splat8(u.f[1]);
        }
      } else {  // bias chunk (slice 7 only): k=4096 -> z=1 (picks up b2), k=4097 -> 0
        #pragma unroll
        for (int m = 0; m < 2; ++m) {
          zs8[m][0] = splat8((_Float16)1.f);
          zs8[m][1] = splat8((_Float16)0.f);
        }
      }

      const char* base = rb + cur * 16384;
      __builtin_amdgcn_s_setprio(1);
      #pragma unroll
      for (int t8 = 0; t8 < 8; ++t8) {            // kstep of 16 joint-kk
        int slot = (t8 * 2 + half_) ^ swo;
        const char* ba = base + slot * 16;
        half8_t bf0 = *(const half8_t*)ba;             // o rows 0..31
        half8_t bf1 = *(const half8_t*)(ba + 8192);    // o rows 32..63 (same swizzle)
        #pragma unroll
        for (int m = 0; m < 2; ++m) {
          half8_t af = xh8[m][t8 & 3] * zs8[m][t8 >> 2];
          acc[m][0] = __builtin_amdgcn_mfma_f32_32x32x16_f16(af, bf0, acc[m][0], 0, 0, 0);
          acc[m][1] = __builtin_amdgcn_mfma_f32_32x32x16_f16(af, bf1, acc[m][1], 0, 0, 0);
        }
      }
      __builtin_amdgcn_s_setprio(0);

      __syncthreads();   // drains this chunk's DMA + all waves done reading Bl[cur]
      cur ^= 1;
    }

    // epilogue: 32x32 C/D layout: col=lane&31, row=(reg&3)+8*(reg>>2)+4*(lane>>5)
    if (PART) {
      float* pb = outbuf + ((size_t)ks * EPAD + e0 + w * 64) * 64 + lane31;
      #pragma unroll
      for (int m = 0; m < 2; ++m) {
        #pragma unroll
        for (int r = 0; r < 16; ++r) {
          int row = m * 32 + (r & 3) + 8 * (r >> 2) + 4 * half_;
          pb[(size_t)row * 64]      = acc[m][0][r];
          pb[(size_t)row * 64 + 32] = acc[m][1][r];
        }
      }
    } else {
      #pragma unroll
      for (int m = 0; m < 2; ++m) {
        #pragma unroll
        for (int r = 0; r < 16; ++r) {
          int e = e0 + w * 64 + m * 32 + (r & 3) + 8 * (r >> 2) + 4 * half_;
          if (e < N_EDGES) {
            int dst = ei[N_EDGES + e];
            atomicAdd(&outbuf[dst * 64 + lane31],      acc[m][0][r]);
            atomicAdd(&outbuf[dst * 64 + lane31 + 32], acc[m][1][r]);
          }
        }
      }
    }

    // grab next tile from the queue (exclusive-write tiles -> deterministic output)
    if (t == 0) nt_sh = NBLOCKS + atomicAdd(counter, 1);
    __syncthreads();
    tile = nt_sh;
  }
}

// ---------------- reduce 8 partial slices -> scatter into agg1 (8x fewer atomics)
__global__ void reduce_partials(const float* __restrict__ P8, const int* __restrict__ ei,
                                float* __restrict__ agg1) {
  int gid = blockIdx.x * 256 + threadIdx.x;
  if (gid >= N_EDGES * 64) return;
  int e = gid >> 6;
  float s = 0.f;
  #pragma unroll
  for (int ks = 0; ks < 8; ++ks) s += P8[(size_t)ks * PSLICE + gid];
  int dst = ei[N_EDGES + e];
  atomicAdd(&agg1[dst * 64 + (gid & 63)], s);
}

// ---------------- node update 1 + global mean pool accumulate
__global__ void node1_pool(const int* __restrict__ batch, const float* __restrict__ x1,
                           const float* __restrict__ agg1, const float* __restrict__ cnt,
                           const float* __restrict__ root1, const float* __restrict__ bias1,
                           float* __restrict__ psum) {
  __shared__ float rt[4096];
  int t = threadIdx.x;
  for (int idx = t; idx < 4096; idx += 256) rt[idx] = root1[idx];
  __syncthreads();
  int w = t >> 6, l = t & 63;
  int n = blockIdx.x * 4 + w;
  if (n >= N_NODES) return;
  float c = fmaxf(cnt[n], 1.f);
  float acc = agg1[n * 64 + l] / c + bias1[l];
  const float* xp = x1 + n * 64;
  #pragma unroll
  for (int i4 = 0; i4 < 16; ++i4) {
    float4 xv = *(const float4*)(xp + i4 * 4);
    acc += xv.x * rt[(i4 * 4 + 0) * 64 + l] + xv.y * rt[(i4 * 4 + 1) * 64 + l]
         + xv.z * rt[(i4 * 4 + 2) * 64 + l] + xv.w * rt[(i4 * 4 + 3) * 64 + l];
  }
  acc = fmaxf(acc, 0.f);
  atomicAdd(&psum[batch[n] * 64 + l], acc);
}

// ---------------- classifier head: one wave per graph
__global__ void classifier(const float* __restrict__ psum, const float* __restrict__ pcnt,
                           const float* __restrict__ wc1, const float* __restrict__ bc1,
                           const float* __restrict__ wc2, const float* __restrict__ bc2,
                           float* __restrict__ out) {
  __shared__ float hb[64];
  int g = blockIdx.x, j = threadIdx.x;
  float c = fmaxf(pcnt[g], 1.f);
  float h = bc1[j];
  const float* pp = psum + g * 64;
  #pragma unroll
  for (int i4 = 0; i4 < 16; ++i4) {
    float4 pv = *(const float4*)(pp + i4 * 4);
    h += (pv.x / c) * wc1[(i4 * 4 + 0) * 64 + j] + (pv.y / c) * wc1[(i4 * 4 + 1) * 64 + j]
       + (pv.z / c) * wc1[(i4 * 4 + 2) * 64 + j] + (pv.w / c) * wc1[(i4 * 4 + 3) * 64 + j];
  }
  hb[j] = fmaxf(h, 0.f);
  __syncthreads();
  if (j < 4) {
    float o = bc2[j];
    #pragma unroll
    for (int k = 0; k < 64; ++k) o += hb[k] * wc2[k * 4 + j];
    out[g * 4 + j] = o;
  }
}

extern "C" void kernel_launch(void* const* d_in, const int* in_sizes, int n_in,
                              void* d_out, int out_size, void* d_ws, size_t ws_size,
                              hipStream_t stream) {
  const float* node_ids = (const float*)d_in[0];
  const int*   ei       = (const int*)d_in[1];
  const float* ea       = (const float*)d_in[2];
  const int*   batch    = (const int*)d_in[3];
  const float* w1_0 = (const float*)d_in[4];
  const float* b1_0 = (const float*)d_in[5];
  const float* w2_0 = (const float*)d_in[6];
  const float* b2_0 = (const float*)d_in[7];
  const float* root0 = (const float*)d_in[8];
  const float* bias0 = (const float*)d_in[9];
  const float* w1_1 = (const float*)d_in[10];
  const float* b1_1 = (const float*)d_in[11];
  const float* w2_1 = (const float*)d_in[12];
  const float* b2_1 = (const float*)d_in[13];
  const float* root1 = (const float*)d_in[14];
  const float* bias1 = (const float*)d_in[15];
  const float* wc1 = (const float*)d_in[16];
  const float* bc1 = (const float*)d_in[17];
  const float* wc2 = (const float*)d_in[18];
  const float* bc2 = (const float*)d_in[19];
  float* out = (float*)d_out;

  char* ws = (char*)d_ws;
  _Float16* BC = (_Float16*)ws;                        // 33,685,504 B (8*257*16384)
  float* x1   = (float*)(ws + 33685504);               //  2,560,000 B
  float* agg0 = (float*)(ws + 36245504);               //  2,560,000 B (zeroed)
  float* agg1 = (float*)(ws + 38805504);               //  2,560,000 B (zeroed)
  float* cnt  = (float*)(ws + 41365504);               //     40,000 B (zeroed)
  float* psum = (float*)(ws + 41405504);               //     16,384 B (zeroed)
  float* pcnt = (float*)(ws + 41421888);               //        256 B (zeroed)
  int*   ctr  = (int*)  (ws + 41422144);               //        256 B (zeroed)
  float* P8   = (float*)(ws + 41422400);               // 82,313,216 B (fully overwritten)
  const size_t NEED_PART = 41422400ull + (size_t)8 * PSLICE * 4;

  (void)hipMemsetAsync(agg0, 0, 2560000 + 2560000 + 40000 + 16384 + 256 + 256, stream);

  prep_B<<<(8 * CPS * 64 + 255) / 256, 256, 0, stream>>>(w2_1, b2_1, BC);
  layer0_edge<<<512, 256, 0, stream>>>(node_ids, ei, ea, w1_0, b1_0, w2_0, b2_0, agg0, cnt);
  node0<<<(N_NODES * 64 + 255) / 256, 256, 0, stream>>>(node_ids, batch, agg0, cnt, root0, bias0, x1, pcnt);

  if (ws_size >= NEED_PART) {
    fused_edge_gemm<true><<<NBLOCKS, 256, 0, stream>>>(ei, ea, x1, w1_1, b1_1, BC, P8, ctr);
    reduce_partials<<<(N_EDGES * 64) / 256, 256, 0, stream>>>(P8, ei, agg1);
  } else {
    fused_edge_gemm<false><<<NBLOCKS, 256, 0, stream>>>(ei, ea, x1, w1_1, b1_1, BC, agg1, ctr);
  }

  node1_pool<<<(N_NODES + 3) / 4, 256, 0, stream>>>(batch, x1, agg1, cnt, root1, bias1, psum);
  classifier<<<N_GRAPH, 64, 0, stream>>>(psum, pcnt, wc1, bc1, wc2, bc2, out);
}

// Round 10
// 1391.029 us; speedup vs baseline: 1.0619x; 1.0104x over previous
//
#include <hip/hip_runtime.h>
#include <hip/hip_fp16.h>

#define N_NODES 10000
#define N_EDGES 40000
#define N_GRAPH 64
#define CPS     258             // chunks per slice: 256 real + bias(ks7)/pad + pad
#define NTILES  1256            // 157 edge-blocks * 8 K-slices
#define EPAD    40192           // 157 * 256 padded edge count
#define PSLICE  (EPAD * 64)     // floats per partial slice

typedef _Float16 half8_t  __attribute__((ext_vector_type(8)));
typedef float    floatx16 __attribute__((ext_vector_type(16)));

__device__ __forceinline__ void gload_lds16(const void* g, void* l) {
  __builtin_amdgcn_global_load_lds((const __attribute__((address_space(1))) void*)g,
                                   (__attribute__((address_space(3))) void*)l, 16, 0, 0);
}

// swizzle: 16B-slot permutation within each row's 256B chunk image (row bits 0-2)
__device__ __host__ __forceinline__ int swz(int row) {
  return ((row & 3) << 1) | ((row >> 2) & 1);
}

__device__ __forceinline__ half8_t splat8(_Float16 v) {
  half8_t r = {v, v, v, v, v, v, v, v};
  return r;
}

union U32H2 { unsigned int u; __half2 h2; };

// ---------------- prep: BC[ks][c][row][128 halves], chunk-major, PRE-SWIZZLED.
// logical B'[o][kk_l] = w2_1[k][i*64+o] (kk_l = k*64+i); slice7 chunk256 = bias rank;
// all other c>=256 chunks zeroed (uniform 258-chunk schedule computes them harmlessly).
__global__ void prep_B(const float* __restrict__ w2, const float* __restrict__ b2,
                       _Float16* __restrict__ BC) {
  int tid = blockIdx.x * 256 + threadIdx.x;
  if (tid >= 8 * CPS * 64) return;
  int ks  = tid / (CPS * 64);
  int rem = tid - ks * (CPS * 64);
  int c = rem >> 6;
  int o = rem & 63;
  _Float16* dst = BC + (size_t)tid * 128;
  if (c > 256 || (c == 256 && ks != 7)) {   // zero pad chunk
    for (int j = 0; j < 128; ++j) dst[j] = (_Float16)0.f;
    return;
  }
  int swo = swz(o);
  int kkbase = ks * 32768 + c * 128;
  for (int sp = 0; sp < 16; ++sp) {         // physical 16B slot
    int kk0 = kkbase + ((sp ^ swo) * 8);    // logical joint-kk of this slot
    #pragma unroll
    for (int j3 = 0; j3 < 8; ++j3) {
      int kk_l = kk0 + j3;
      int k = kk_l >> 6, i = kk_l & 63;
      float v;
      if (k < 4096)       v = w2[k * 4096 + i * 64 + o];
      else if (k == 4096) v = b2[i * 64 + o];
      else                v = 0.f;
      dst[sp * 8 + j3] = (_Float16)v;
    }
  }
}

// ---------------- prep W: WP[ks][c][8 u32] = {w1 pairs d0..d3, b1 pair, 0,0,0} as half2
__global__ void prep_W(const float* __restrict__ w1, const float* __restrict__ b1,
                       unsigned int* __restrict__ WP) {
  int tid = blockIdx.x * 256 + threadIdx.x;
  if (tid >= 8 * 256) return;
  int ks = tid >> 8, c = tid & 255;
  int kb = ks * 512 + 2 * c;
  unsigned int* dst = WP + (size_t)tid * 8;
  #pragma unroll
  for (int d = 0; d < 4; ++d) {
    float2 v = *(const float2*)(w1 + d * 4096 + kb);
    U32H2 u; u.h2 = __floats2half2_rn(v.x, v.y);
    dst[d] = u.u;
  }
  float2 bv = *(const float2*)(b1 + kb);
  U32H2 u; u.h2 = __floats2half2_rn(bv.x, bv.y);
  dst[4] = u.u; dst[5] = 0; dst[6] = 0; dst[7] = 0;
}

// ---------------- layer 0: per-edge MLP (in_dim=1) + scatter-sum + degree count
__global__ void layer0_edge(const float* __restrict__ node_ids,
                            const int* __restrict__ ei,
                            const float* __restrict__ ea,
                            const float* __restrict__ w1, const float* __restrict__ b1,
                            const float* __restrict__ w2, const float* __restrict__ b2,
                            float* __restrict__ agg0, float* __restrict__ cnt) {
  __shared__ float w1s[256], b1s[64], w2s[4096], b2s[64], zb[4][64];
  int t = threadIdx.x;
  for (int idx = t; idx < 4096; idx += 256) w2s[idx] = w2[idx];
  if (t < 256) w1s[t] = w1[t];
  if (t < 64) { b1s[t] = b1[t]; b2s[t] = b2[t]; }
  __syncthreads();
  int w = t >> 6, l = t & 63;
  int gw = blockIdx.x * 4 + w;
  int nw = gridDim.x * 4;
  for (int e = gw; e < N_EDGES; e += nw) {
    float a0 = ea[e * 4 + 0], a1 = ea[e * 4 + 1], a2 = ea[e * 4 + 2], a3 = ea[e * 4 + 3];
    float z = a0 * w1s[l] + a1 * w1s[64 + l] + a2 * w1s[128 + l] + a3 * w1s[192 + l] + b1s[l];
    zb[w][l] = fmaxf(z, 0.f);
    asm volatile("s_waitcnt lgkmcnt(0)" ::: "memory");
    __builtin_amdgcn_sched_barrier(0);
    float h = b2s[l];
    #pragma unroll
    for (int k = 0; k < 64; ++k) h += zb[w][k] * w2s[k * 64 + l];
    int src = ei[e], dst = ei[N_EDGES + e];
    float msg = node_ids[src] * h;
    atomicAdd(&agg0[dst * 64 + l], msg);
    if (l == 0) atomicAdd(&cnt[dst], 1.0f);
  }
}

// ---------------- node update 0: x1 = relu(agg0/cnt + node_ids*root0 + bias0); pool counts
__global__ void node0(const float* __restrict__ node_ids, const int* __restrict__ batch,
                      const float* __restrict__ agg0, const float* __restrict__ cnt,
                      const float* __restrict__ root0, const float* __restrict__ bias0,
                      float* __restrict__ x1, float* __restrict__ pcnt) {
  int gid = blockIdx.x * 256 + threadIdx.x;
  if (gid >= N_NODES * 64) return;
  int n = gid >> 6, o = gid & 63;
  float c = fmaxf(cnt[n], 1.f);
  float v = agg0[gid] / c + node_ids[n] * root0[o] + bias0[o];
  x1[gid] = fmaxf(v, 0.f);
  if (o == 0) atomicAdd(&pcnt[batch[n]], 1.0f);
}

// ---------------- layer 1 fused: msg[e,o] = sum_kk (z_e[k]*x_e[i]) * B'[kk,o]
// grid = 1256 (157 eb x 8 ks, ks==blockIdx%8 -> XCD L2 affinity); block = 4 waves.
// Wave: 64 edges x 64 o. 3-buffer LDS ring (48 KB), raw s_barrier + counted
// s_waitcnt vmcnt(4): next-next chunk's DMAs stay in flight across barriers.
// w1/b1 per-chunk params via wave-uniform loads from WP (no LDS).
template <bool PART>
__launch_bounds__(256, 3)
__global__ void fused_edge_gemm(const int* __restrict__ ei,
                                const float* __restrict__ ea,
                                const float* __restrict__ x1,
                                const unsigned int* __restrict__ WP,
                                const _Float16* __restrict__ BC,
                                float* __restrict__ outbuf) {
  __shared__ __attribute__((aligned(16))) _Float16 Bl[3][64 * 128]; // 49152 B
  int t = threadIdx.x;
  int ks = blockIdx.x & 7;
  int eb = blockIdx.x >> 3;
  int e0 = eb * 256;
  int w = t >> 6, l = t & 63;
  int half_ = l >> 5;
  int lane31 = l & 31;
  int swo = swz(lane31);             // same for lane31 and lane31+32 (row bits 0-2)

  // per-lane A data: 2 edge-tiles of 32; lane holds x[row=lane31][q*16+half_*8+0..7]
  half8_t xh8[2][4];
  __half2 eb_bc[2][4];
  #pragma unroll
  for (int m = 0; m < 2; ++m) {
    int e = e0 + w * 64 + m * 32 + lane31;
    if (e < N_EDGES) {
      int src = ei[e];
      const float* xp = x1 + src * 64 + half_ * 8;
      #pragma unroll
      for (int q = 0; q < 4; ++q) {
        float4 f0 = *(const float4*)(xp + q * 16);
        float4 f1 = *(const float4*)(xp + q * 16 + 4);
        half8_t v;
        v[0] = (_Float16)f0.x; v[1] = (_Float16)f0.y;
        v[2] = (_Float16)f0.z; v[3] = (_Float16)f0.w;
        v[4] = (_Float16)f1.x; v[5] = (_Float16)f1.y;
        v[6] = (_Float16)f1.z; v[7] = (_Float16)f1.w;
        xh8[m][q] = v;
      }
      float4 av = *(const float4*)(ea + e * 4);
      eb_bc[m][0] = __float2half2_rn(av.x); eb_bc[m][1] = __float2half2_rn(av.y);
      eb_bc[m][2] = __float2half2_rn(av.z); eb_bc[m][3] = __float2half2_rn(av.w);
    } else {
      #pragma unroll
      for (int q = 0; q < 4; ++q) xh8[m][q] = splat8((_Float16)0.f);
      #pragma unroll
      for (int d = 0; d < 4; ++d) eb_bc[m][d] = __float2half2_rn(0.f);
    }
  }

  floatx16 acc[2][2];
  #pragma unroll
  for (int m = 0; m < 2; ++m)
    #pragma unroll
    for (int n = 0; n < 2; ++n)
      #pragma unroll
      for (int r = 0; r < 16; ++r) acc[m][n][r] = 0.f;

  // addressing
  const char* gp = (const char*)BC + (size_t)ks * (CPS * 16384) + w * 4096 + l * 16;
  char*       sd = (char*)&Bl[0][0] + w * 4096 + l * 16;     // + buf*16384
  const char* rb = (const char*)&Bl[0][0] + lane31 * 256;    // + buf*16384
  const unsigned int* wp = WP + (size_t)ks * 256 * 8;        // uniform per block

  auto stg = [&](int sb) {           // stage next pending chunk into ring buffer sb
    char* d = sd + sb * 16384;
    gload_lds16(gp,        d);
    gload_lds16(gp + 1024, d + 1024);
    gload_lds16(gp + 2048, d + 2048);
    gload_lds16(gp + 3072, d + 3072);
    gp += 16384;
  };

  const __half zero1 = __float2half(0.f);
  union H2F { __half2 h2; _Float16 f[2]; };
  half8_t zs8[2][2];

  auto zgen = [&](int c) {           // z for chunk c's two real k values (uniform WP read)
    uint4 wv = *(const uint4*)(wp + c * 8);
    unsigned int bb = wp[c * 8 + 4];
    U32H2 uw0, uw1, uw2, uw3, ub;
    uw0.u = wv.x; uw1.u = wv.y; uw2.u = wv.z; uw3.u = wv.w; ub.u = bb;
    #pragma unroll
    for (int m = 0; m < 2; ++m) {
      __half2 h = __hfma2(eb_bc[m][0], uw0.h2, ub.h2);
      h = __hfma2(eb_bc[m][1], uw1.h2, h);
      h = __hfma2(eb_bc[m][2], uw2.h2, h);
      h = __hfma2(eb_bc[m][3], uw3.h2, h);
      H2F u; u.h2 = __halves2half2(__hmax(__low2half(h),  zero1),
                                   __hmax(__high2half(h), zero1));
      zs8[m][0] = splat8(u.f[0]);
      zs8[m][1] = splat8(u.f[1]);
    }
  };
  auto zbias = [&]() {               // c>=256: ks7 bias rank (z=1/0); pads have B=0
    #pragma unroll
    for (int m = 0; m < 2; ++m) {
      zs8[m][0] = splat8((_Float16)1.f);
      zs8[m][1] = splat8((_Float16)0.f);
    }
  };

  auto cmp = [&](int rbuf) {         // 32 MFMA on ring buffer rbuf
    const char* base = rb + rbuf * 16384;
    __builtin_amdgcn_s_setprio(1);
    #pragma unroll
    for (int t8 = 0; t8 < 8; ++t8) {
      int slot = (t8 * 2 + half_) ^ swo;
      const char* ba = base + slot * 16;
      half8_t bf0 = *(const half8_t*)ba;             // o rows 0..31
      half8_t bf1 = *(const half8_t*)(ba + 8192);    // o rows 32..63 (same swizzle)
      #pragma unroll
      for (int m = 0; m < 2; ++m) {
        half8_t af = xh8[m][t8 & 3] * zs8[m][t8 >> 2];
        acc[m][0] = __builtin_amdgcn_mfma_f32_32x32x16_f16(af, bf0, acc[m][0], 0, 0, 0);
        acc[m][1] = __builtin_amdgcn_mfma_f32_32x32x16_f16(af, bf1, acc[m][1], 0, 0, 0);
      }
    }
    __builtin_amdgcn_s_setprio(0);
  };

#define SYNC4 do { asm volatile("s_waitcnt vmcnt(4)" ::: "memory"); \
                   __builtin_amdgcn_sched_barrier(0); \
                   __builtin_amdgcn_s_barrier(); \
                   __builtin_amdgcn_sched_barrier(0); } while (0)
#define SYNC0 do { asm volatile("s_waitcnt vmcnt(0)" ::: "memory"); \
                   __builtin_amdgcn_sched_barrier(0); \
                   __builtin_amdgcn_s_barrier(); \
                   __builtin_amdgcn_sched_barrier(0); } while (0)

  // ring prologue: chunks 0,1 in flight
  stg(0); stg(1);

  // phase c: zgen(c); vmcnt(4) certifies chunk c landed (FIFO: stg(c+1)'s 4 loads are
  // newest, so <=4 outstanding => stg(c) retired); barrier; stage c+2 (all waves are
  // past reading that buffer); 32 MFMAs on buf c%3.
  int c = 0;
  for (int it = 0; it < 85; ++it) {  // c = 0..254
    zgen(c);     SYNC4; stg(2); cmp(0);
    zgen(c + 1); SYNC4; stg(0); cmp(1);
    zgen(c + 2); SYNC4; stg(1); cmp(2);
    c += 3;
  }
  // tail: c = 255 (stages chunk 257), 256 (bias/pad), 257 (pad)
  zgen(255); SYNC4; stg(2); cmp(0);
  zbias();   SYNC4;         cmp(1);
  zbias();   SYNC0;         cmp(2);

#undef SYNC4
#undef SYNC0

  // epilogue: 32x32 C/D layout: col=lane&31, row=(reg&3)+8*(reg>>2)+4*(lane>>5)
  if (PART) {
    float* pb = outbuf + ((size_t)ks * EPAD + e0 + w * 64) * 64 + lane31;
    #pragma unroll
    for (int m = 0; m < 2; ++m) {
      #pragma unroll
      for (int r = 0; r < 16; ++r) {
        int row = m * 32 + (r & 3) + 8 * (r >> 2) + 4 * half_;
        pb[(size_t)row * 64]      = acc[m][0][r];
        pb[(size_t)row * 64 + 32] = acc[m][1][r];
      }
    }
  } else {
    #pragma unroll
    for (int m = 0; m < 2; ++m) {
      #pragma unroll
      for (int r = 0; r < 16; ++r) {
        int e = e0 + w * 64 + m * 32 + (r & 3) + 8 * (r >> 2) + 4 * half_;
        if (e < N_EDGES) {
          int dst = ei[N_EDGES + e];
          atomicAdd(&outbuf[dst * 64 + lane31],      acc[m][0][r]);
          atomicAdd(&outbuf[dst * 64 + lane31 + 32], acc[m][1][r]);
        }
      }
    }
  }
}

// ---------------- reduce 8 partial slices -> scatter into agg1 (8x fewer atomics)
__global__ void reduce_partials(const float* __restrict__ P8, const int* __restrict__ ei,
                                float* __restrict__ agg1) {
  int gid = blockIdx.x * 256 + threadIdx.x;
  if (gid >= N_EDGES * 64) return;
  int e = gid >> 6;
  float s = 0.f;
  #pragma unroll
  for (int ks = 0; ks < 8; ++ks) s += P8[(size_t)ks * PSLICE + gid];
  int dst = ei[N_EDGES + e];
  atomicAdd(&agg1[dst * 64 + (gid & 63)], s);
}

// ---------------- node update 1 + global mean pool accumulate
__global__ void node1_pool(const int* __restrict__ batch, const float* __restrict__ x1,
                           const float* __restrict__ agg1, const float* __restrict__ cnt,
                           const float* __restrict__ root1, const float* __restrict__ bias1,
                           float* __restrict__ psum) {
  __shared__ float rt[4096];
  int t = threadIdx.x;
  for (int idx = t; idx < 4096; idx += 256) rt[idx] = root1[idx];
  __syncthreads();
  int w = t >> 6, l = t & 63;
  int n = blockIdx.x * 4 + w;
  if (n >= N_NODES) return;
  float c = fmaxf(cnt[n], 1.f);
  float acc = agg1[n * 64 + l] / c + bias1[l];
  const float* xp = x1 + n * 64;
  #pragma unroll
  for (int i4 = 0; i4 < 16; ++i4) {
    float4 xv = *(const float4*)(xp + i4 * 4);
    acc += xv.x * rt[(i4 * 4 + 0) * 64 + l] + xv.y * rt[(i4 * 4 + 1) * 64 + l]
         + xv.z * rt[(i4 * 4 + 2) * 64 + l] + xv.w * rt[(i4 * 4 + 3) * 64 + l];
  }
  acc = fmaxf(acc, 0.f);
  atomicAdd(&psum[batch[n] * 64 + l], acc);
}

// ---------------- classifier head: one wave per graph
__global__ void classifier(const float* __restrict__ psum, const float* __restrict__ pcnt,
                           const float* __restrict__ wc1, const float* __restrict__ bc1,
                           const float* __restrict__ wc2, const float* __restrict__ bc2,
                           float* __restrict__ out) {
  __shared__ float hb[64];
  int g = blockIdx.x, j = threadIdx.x;
  float c = fmaxf(pcnt[g], 1.f);
  float h = bc1[j];
  const float* pp = psum + g * 64;
  #pragma unroll
  for (int i4 = 0; i4 < 16; ++i4) {
    float4 pv = *(const float4*)(pp + i4 * 4);
    h += (pv.x / c) * wc1[(i4 * 4 + 0) * 64 + j] + (pv.y / c) * wc1[(i4 * 4 + 1) * 64 + j]
       + (pv.z / c) * wc1[(i4 * 4 + 2) * 64 + j] + (pv.w / c) * wc1[(i4 * 4 + 3) * 64 + j];
  }
  hb[j] = fmaxf(h, 0.f);
  __syncthreads();
  if (j < 4) {
    float o = bc2[j];
    #pragma unroll
    for (int k = 0; k < 64; ++k) o += hb[k] * wc2[k * 4 + j];
    out[g * 4 + j] = o;
  }
}

extern "C" void kernel_launch(void* const* d_in, const int* in_sizes, int n_in,
                              void* d_out, int out_size, void* d_ws, size_t ws_size,
                              hipStream_t stream) {
  const float* node_ids = (const float*)d_in[0];
  const int*   ei       = (const int*)d_in[1];
  const float* ea       = (const float*)d_in[2];
  const int*   batch    = (const int*)d_in[3];
  const float* w1_0 = (const float*)d_in[4];
  const float* b1_0 = (const float*)d_in[5];
  const float* w2_0 = (const float*)d_in[6];
  const float* b2_0 = (const float*)d_in[7];
  const float* root0 = (const float*)d_in[8];
  const float* bias0 = (const float*)d_in[9];
  const float* w1_1 = (const float*)d_in[10];
  const float* b1_1 = (const float*)d_in[11];
  const float* w2_1 = (const float*)d_in[12];
  const float* b2_1 = (const float*)d_in[13];
  const float* root1 = (const float*)d_in[14];
  const float* bias1 = (const float*)d_in[15];
  const float* wc1 = (const float*)d_in[16];
  const float* bc1 = (const float*)d_in[17];
  const float* wc2 = (const float*)d_in[18];
  const float* bc2 = (const float*)d_in[19];
  float* out = (float*)d_out;

  char* ws = (char*)d_ws;
  _Float16* BC = (_Float16*)ws;                        // 33,816,576 B (8*258*16384)
  unsigned int* WP = (unsigned int*)(ws + 33816576);   //     65,536 B (8*256*32)
  float* x1   = (float*)(ws + 33882112);               //  2,560,000 B
  float* agg0 = (float*)(ws + 36442112);               //  2,560,000 B (zeroed)
  float* agg1 = (float*)(ws + 39002112);               //  2,560,000 B (zeroed)
  float* cnt  = (float*)(ws + 41562112);               //     40,000 B (zeroed)
  float* psum = (float*)(ws + 41602112);               //     16,384 B (zeroed)
  float* pcnt = (float*)(ws + 41618496);               //        256 B (zeroed)
  float* P8   = (float*)(ws + 41618752);               // 82,313,216 B (fully overwritten)
  const size_t NEED_PART = 41618752ull + (size_t)8 * PSLICE * 4;

  (void)hipMemsetAsync(agg0, 0, 2560000 + 2560000 + 40000 + 16384 + 256, stream);

  prep_B<<<(8 * CPS * 64 + 255) / 256, 256, 0, stream>>>(w2_1, b2_1, BC);
  prep_W<<<8, 256, 0, stream>>>(w1_1, b1_1, WP);
  layer0_edge<<<512, 256, 0, stream>>>(node_ids, ei, ea, w1_0, b1_0, w2_0, b2_0, agg0, cnt);
  node0<<<(N_NODES * 64 + 255) / 256, 256, 0, stream>>>(node_ids, batch, agg0, cnt, root0, bias0, x1, pcnt);

  if (ws_size >= NEED_PART) {
    fused_edge_gemm<true><<<NTILES, 256, 0, stream>>>(ei, ea, x1, WP, BC, P8);
    reduce_partials<<<(N_EDGES * 64) / 256, 256, 0, stream>>>(P8, ei, agg1);
  } else {
    fused_edge_gemm<false><<<NTILES, 256, 0, stream>>>(ei, ea, x1, WP, BC, agg1);
  }

  node1_pool<<<(N_NODES + 3) / 4, 256, 0, stream>>>(batch, x1, agg1, cnt, root1, bias1, psum);
  classifier<<<N_GRAPH, 64, 0, stream>>>(psum, pcnt, wc1, bc1, wc2, bc2, out);
}

// Round 11
// 1345.502 us; speedup vs baseline: 1.0979x; 1.0338x over previous
//
#include <hip/hip_runtime.h>
#include <hip/hip_fp16.h>

#define N_NODES 10000
#define N_EDGES 40000
#define N_GRAPH 64
#define CPS     258             // chunks per slice: 256 real + bias(ks7)/pad + pad
#define NTILES  1256            // 157 edge-blocks * 8 K-slices
#define EPAD    40192           // 157 * 256 padded edge count
#define PSLICE  (EPAD * 64)     // floats per partial slice

typedef _Float16 half8_t  __attribute__((ext_vector_type(8)));
typedef float    floatx16 __attribute__((ext_vector_type(16)));

__device__ __forceinline__ void gload_lds16(const void* g, void* l) {
  __builtin_amdgcn_global_load_lds((const __attribute__((address_space(1))) void*)g,
                                   (__attribute__((address_space(3))) void*)l, 16, 0, 0);
}

// swizzle: 16B-slot permutation within each row's 256B chunk image (row bits 0-2)
__device__ __host__ __forceinline__ int swz(int row) {
  return ((row & 3) << 1) | ((row >> 2) & 1);
}

__device__ __forceinline__ half8_t splat8(_Float16 v) {
  half8_t r = {v, v, v, v, v, v, v, v};
  return r;
}

union U32H2 { unsigned int u; __half2 h2; };

// ---------------- prep v3: BC[ks][c][o][128], chunk-major pre-swizzled image.
// Thread per (ks, c, pos=logical kk within chunk); o-loop reads w2 row CONTIGUOUSLY
// (256 B/thread) and scatters the 2B writes so each wave covers full 128B segments.
__global__ void prep_B(const float* __restrict__ w2, const float* __restrict__ b2,
                       _Float16* __restrict__ BC) {
  int tid = blockIdx.x * 256 + threadIdx.x;
  if (tid >= 8 * CPS * 128) return;
  int ks  = tid / (CPS * 128);
  int rem = tid - ks * (CPS * 128);
  int c   = rem >> 7;
  int pos = rem & 127;
  int sl = pos >> 3, j3 = pos & 7;
  _Float16* dstb = BC + ((size_t)(ks * CPS + c) * 64) * 128;
  bool pad = (c > 256) || (c == 256 && ks != 7);
  int kk_l = ks * 32768 + c * 128 + pos;
  int k = kk_l >> 6, i = kk_l & 63;
  if (pad || k > 4096) {
    #pragma unroll 8
    for (int o = 0; o < 64; ++o)
      dstb[o * 128 + ((sl ^ swz(o)) << 3) + j3] = (_Float16)0.f;
  } else if (k < 4096) {
    const float* src = w2 + (size_t)k * 4096 + i * 64;
    #pragma unroll 8
    for (int o = 0; o < 64; ++o)
      dstb[o * 128 + ((sl ^ swz(o)) << 3) + j3] = (_Float16)src[o];
  } else {                       // k == 4096: bias rank (ks7 c256 pos<64)
    const float* src = b2 + i * 64;
    #pragma unroll 8
    for (int o = 0; o < 64; ++o)
      dstb[o * 128 + ((sl ^ swz(o)) << 3) + j3] = (_Float16)src[o];
  }
}

// ---------------- prep W: WP[ks][c][8 u32] = {w1 pairs d0..d3, b1 pair, 0,0,0} as half2
__global__ void prep_W(const float* __restrict__ w1, const float* __restrict__ b1,
                       unsigned int* __restrict__ WP) {
  int tid = blockIdx.x * 256 + threadIdx.x;
  if (tid >= 8 * 256) return;
  int ks = tid >> 8, c = tid & 255;
  int kb = ks * 512 + 2 * c;
  unsigned int* dst = WP + (size_t)tid * 8;
  #pragma unroll
  for (int d = 0; d < 4; ++d) {
    float2 v = *(const float2*)(w1 + d * 4096 + kb);
    U32H2 u; u.h2 = __floats2half2_rn(v.x, v.y);
    dst[d] = u.u;
  }
  float2 bv = *(const float2*)(b1 + kb);
  U32H2 u; u.h2 = __floats2half2_rn(bv.x, bv.y);
  dst[4] = u.u; dst[5] = 0; dst[6] = 0; dst[7] = 0;
}

// ---------------- layer 0: per-edge MLP (in_dim=1) + scatter-sum + degree count
__global__ void layer0_edge(const float* __restrict__ node_ids,
                            const int* __restrict__ ei,
                            const float* __restrict__ ea,
                            const float* __restrict__ w1, const float* __restrict__ b1,
                            const float* __restrict__ w2, const float* __restrict__ b2,
                            float* __restrict__ agg0, float* __restrict__ cnt) {
  __shared__ float w1s[256], b1s[64], w2s[4096], b2s[64], zb[4][64];
  int t = threadIdx.x;
  for (int idx = t; idx < 4096; idx += 256) w2s[idx] = w2[idx];
  if (t < 256) w1s[t] = w1[t];
  if (t < 64) { b1s[t] = b1[t]; b2s[t] = b2[t]; }
  __syncthreads();
  int w = t >> 6, l = t & 63;
  int gw = blockIdx.x * 4 + w;
  int nw = gridDim.x * 4;
  for (int e = gw; e < N_EDGES; e += nw) {
    float a0 = ea[e * 4 + 0], a1 = ea[e * 4 + 1], a2 = ea[e * 4 + 2], a3 = ea[e * 4 + 3];
    float z = a0 * w1s[l] + a1 * w1s[64 + l] + a2 * w1s[128 + l] + a3 * w1s[192 + l] + b1s[l];
    zb[w][l] = fmaxf(z, 0.f);
    asm volatile("s_waitcnt lgkmcnt(0)" ::: "memory");
    __builtin_amdgcn_sched_barrier(0);
    float h = b2s[l];
    #pragma unroll
    for (int k = 0; k < 64; ++k) h += zb[w][k] * w2s[k * 64 + l];
    int src = ei[e], dst = ei[N_EDGES + e];
    float msg = node_ids[src] * h;
    atomicAdd(&agg0[dst * 64 + l], msg);
    if (l == 0) atomicAdd(&cnt[dst], 1.0f);
  }
}

// ---------------- node update 0: x1 = relu(agg0/cnt + node_ids*root0 + bias0); pool counts
__global__ void node0(const float* __restrict__ node_ids, const int* __restrict__ batch,
                      const float* __restrict__ agg0, const float* __restrict__ cnt,
                      const float* __restrict__ root0, const float* __restrict__ bias0,
                      float* __restrict__ x1, float* __restrict__ pcnt) {
  int gid = blockIdx.x * 256 + threadIdx.x;
  if (gid >= N_NODES * 64) return;
  int n = gid >> 6, o = gid & 63;
  float c = fmaxf(cnt[n], 1.f);
  float v = agg0[gid] / c + node_ids[n] * root0[o] + bias0[o];
  x1[gid] = fmaxf(v, 0.f);
  if (o == 0) atomicAdd(&pcnt[batch[n]], 1.0f);
}

// ---------------- layer 1 fused: msg[e,o] = sum_kk (z_e[k]*x_e[i]) * B'[kk,o]
// grid = 1256 (157 eb x 8 ks); block = 4 waves = 2 edge-groups x 2 o-groups.
// Wave: 128 edges (m=4) x 32 o (n=1): B-read per MFMA halves vs 64x64 geometry.
// 3-buffer LDS ring (48 KB), raw s_barrier + counted vmcnt(4).
template <bool PART>
__launch_bounds__(256, 3)
__global__ void fused_edge_gemm(const int* __restrict__ ei,
                                const float* __restrict__ ea,
                                const float* __restrict__ x1,
                                const unsigned int* __restrict__ WP,
                                const _Float16* __restrict__ BC,
                                float* __restrict__ outbuf) {
  __shared__ __attribute__((aligned(16))) _Float16 Bl[3][64 * 128]; // 49152 B
  int t = threadIdx.x;
  int ks = blockIdx.x & 7;
  int eb = blockIdx.x >> 3;
  int e0 = eb * 256;
  int w = t >> 6, l = t & 63;
  int half_ = l >> 5;
  int lane31 = l & 31;
  int wr = w >> 1;                   // edge group: 128 edges
  int wc = w & 1;                    // o group: 32 outputs
  int swo = swz(lane31);             // row bits 0-2 only

  // per-lane A data: 4 edge-tiles of 32; lane holds x[row=lane31][q*16+half_*8+0..7]
  half8_t xh8[4][4];
  __half2 ea01[4], ea23[4];
  #pragma unroll
  for (int m = 0; m < 4; ++m) {
    int e = e0 + wr * 128 + m * 32 + lane31;
    if (e < N_EDGES) {
      int src = ei[e];
      const float* xp = x1 + src * 64 + half_ * 8;
      #pragma unroll
      for (int q = 0; q < 4; ++q) {
        float4 f0 = *(const float4*)(xp + q * 16);
        float4 f1 = *(const float4*)(xp + q * 16 + 4);
        half8_t v;
        v[0] = (_Float16)f0.x; v[1] = (_Float16)f0.y;
        v[2] = (_Float16)f0.z; v[3] = (_Float16)f0.w;
        v[4] = (_Float16)f1.x; v[5] = (_Float16)f1.y;
        v[6] = (_Float16)f1.z; v[7] = (_Float16)f1.w;
        xh8[m][q] = v;
      }
      float4 av = *(const float4*)(ea + e * 4);
      ea01[m] = __floats2half2_rn(av.x, av.y);
      ea23[m] = __floats2half2_rn(av.z, av.w);
    } else {
      #pragma unroll
      for (int q = 0; q < 4; ++q) xh8[m][q] = splat8((_Float16)0.f);
      ea01[m] = __floats2half2_rn(0.f, 0.f);
      ea23[m] = __floats2half2_rn(0.f, 0.f);
    }
  }

  floatx16 acc[4];
  #pragma unroll
  for (int m = 0; m < 4; ++m)
    #pragma unroll
    for (int r = 0; r < 16; ++r) acc[m][r] = 0.f;

  // addressing
  const char* gp = (const char*)BC + (size_t)ks * (CPS * 16384) + w * 4096 + l * 16;
  char*       sd = (char*)&Bl[0][0] + w * 4096 + l * 16;           // + buf*16384
  const char* rb = (const char*)&Bl[0][0] + (wc * 32 + lane31) * 256;  // + buf*16384
  const unsigned int* wp = WP + (size_t)ks * 256 * 8;              // uniform per block

  auto stg = [&](int sb) {           // stage next pending chunk into ring buffer sb
    char* d = sd + sb * 16384;
    gload_lds16(gp,        d);
    gload_lds16(gp + 1024, d + 1024);
    gload_lds16(gp + 2048, d + 2048);
    gload_lds16(gp + 3072, d + 3072);
    gp += 16384;
  };

  const __half zero1 = __float2half(0.f);
  union H2F { __half2 h2; _Float16 f[2]; };
  half8_t zs8[4][2];

  auto zgen = [&](int c) {           // z for chunk c's two real k values (uniform WP read)
    uint4 wv = *(const uint4*)(wp + c * 8);
    unsigned int bb = wp[c * 8 + 4];
    U32H2 uw0, uw1, uw2, uw3, ub;
    uw0.u = wv.x; uw1.u = wv.y; uw2.u = wv.z; uw3.u = wv.w; ub.u = bb;
    #pragma unroll
    for (int m = 0; m < 4; ++m) {
      __half2 h = __hfma2(__half2half2(__low2half(ea01[m])),  uw0.h2, ub.h2);
      h = __hfma2(__half2half2(__high2half(ea01[m])), uw1.h2, h);
      h = __hfma2(__half2half2(__low2half(ea23[m])),  uw2.h2, h);
      h = __hfma2(__half2half2(__high2half(ea23[m])), uw3.h2, h);
      H2F u; u.h2 = __halves2half2(__hmax(__low2half(h),  zero1),
                                   __hmax(__high2half(h), zero1));
      zs8[m][0] = splat8(u.f[0]);
      zs8[m][1] = splat8(u.f[1]);
    }
  };
  auto zbias = [&]() {               // c>=256: ks7 bias rank (z=1/0); pads have B=0
    #pragma unroll
    for (int m = 0; m < 4; ++m) {
      zs8[m][0] = splat8((_Float16)1.f);
      zs8[m][1] = splat8((_Float16)0.f);
    }
  };

  auto cmp = [&](int rbuf) {         // 32 MFMA on ring buffer rbuf (1 B-read per k-step)
    const char* base = rb + rbuf * 16384;
    __builtin_amdgcn_s_setprio(1);
    #pragma unroll
    for (int t8 = 0; t8 < 8; ++t8) {
      int slot = (t8 * 2 + half_) ^ swo;
      half8_t bf = *(const half8_t*)(base + slot * 16);
      #pragma unroll
      for (int m = 0; m < 4; ++m) {
        half8_t af = xh8[m][t8 & 3] * zs8[m][t8 >> 2];
        acc[m] = __builtin_amdgcn_mfma_f32_32x32x16_f16(af, bf, acc[m], 0, 0, 0);
      }
    }
    __builtin_amdgcn_s_setprio(0);
  };

#define SYNC4 do { asm volatile("s_waitcnt vmcnt(4)" ::: "memory"); \
                   __builtin_amdgcn_sched_barrier(0); \
                   __builtin_amdgcn_s_barrier(); \
                   __builtin_amdgcn_sched_barrier(0); } while (0)
#define SYNC0 do { asm volatile("s_waitcnt vmcnt(0)" ::: "memory"); \
                   __builtin_amdgcn_sched_barrier(0); \
                   __builtin_amdgcn_s_barrier(); \
                   __builtin_amdgcn_sched_barrier(0); } while (0)

  // ring prologue: chunks 0,1 in flight
  stg(0); stg(1);

  int c = 0;
  for (int it = 0; it < 85; ++it) {  // c = 0..254
    zgen(c);     SYNC4; stg(2); cmp(0);
    zgen(c + 1); SYNC4; stg(0); cmp(1);
    zgen(c + 2); SYNC4; stg(1); cmp(2);
    c += 3;
  }
  // tail: c = 255 (stages chunk 257), 256 (bias/pad), 257 (pad)
  zgen(255); SYNC4; stg(2); cmp(0);
  zbias();   SYNC4;         cmp(1);
  zbias();   SYNC0;         cmp(2);

#undef SYNC4
#undef SYNC0

  // epilogue: 32x32 C/D layout: col=lane&31, row=(reg&3)+8*(reg>>2)+4*(lane>>5)
  if (PART) {
    float* pb = outbuf + ((size_t)ks * EPAD + e0 + wr * 128) * 64 + wc * 32 + lane31;
    #pragma unroll
    for (int m = 0; m < 4; ++m) {
      #pragma unroll
      for (int r = 0; r < 16; ++r) {
        int row = m * 32 + (r & 3) + 8 * (r >> 2) + 4 * half_;
        pb[(size_t)row * 64] = acc[m][r];
      }
    }
  } else {
    #pragma unroll
    for (int m = 0; m < 4; ++m) {
      #pragma unroll
      for (int r = 0; r < 16; ++r) {
        int e = e0 + wr * 128 + m * 32 + (r & 3) + 8 * (r >> 2) + 4 * half_;
        if (e < N_EDGES) {
          int dst = ei[N_EDGES + e];
          atomicAdd(&outbuf[dst * 64 + wc * 32 + lane31], acc[m][r]);
        }
      }
    }
  }
}

// ---------------- reduce 8 partial slices -> scatter into agg1 (8x fewer atomics)
__global__ void reduce_partials(const float* __restrict__ P8, const int* __restrict__ ei,
                                float* __restrict__ agg1) {
  int gid = blockIdx.x * 256 + threadIdx.x;
  if (gid >= N_EDGES * 64) return;
  int e = gid >> 6;
  float s = 0.f;
  #pragma unroll
  for (int ks = 0; ks < 8; ++ks) s += P8[(size_t)ks * PSLICE + gid];
  int dst = ei[N_EDGES + e];
  atomicAdd(&agg1[dst * 64 + (gid & 63)], s);
}

// ---------------- node update 1 + global mean pool accumulate
__global__ void node1_pool(const int* __restrict__ batch, const float* __restrict__ x1,
                           const float* __restrict__ agg1, const float* __restrict__ cnt,
                           const float* __restrict__ root1, const float* __restrict__ bias1,
                           float* __restrict__ psum) {
  __shared__ float rt[4096];
  int t = threadIdx.x;
  for (int idx = t; idx < 4096; idx += 256) rt[idx] = root1[idx];
  __syncthreads();
  int w = t >> 6, l = t & 63;
  int n = blockIdx.x * 4 + w;
  if (n >= N_NODES) return;
  float c = fmaxf(cnt[n], 1.f);
  float acc = agg1[n * 64 + l] / c + bias1[l];
  const float* xp = x1 + n * 64;
  #pragma unroll
  for (int i4 = 0; i4 < 16; ++i4) {
    float4 xv = *(const float4*)(xp + i4 * 4);
    acc += xv.x * rt[(i4 * 4 + 0) * 64 + l] + xv.y * rt[(i4 * 4 + 1) * 64 + l]
         + xv.z * rt[(i4 * 4 + 2) * 64 + l] + xv.w * rt[(i4 * 4 + 3) * 64 + l];
  }
  acc = fmaxf(acc, 0.f);
  atomicAdd(&psum[batch[n] * 64 + l], acc);
}

// ---------------- classifier head: one wave per graph
__global__ void classifier(const float* __restrict__ psum, const float* __restrict__ pcnt,
                           const float* __restrict__ wc1, const float* __restrict__ bc1,
                           const float* __restrict__ wc2, const float* __restrict__ bc2,
                           float* __restrict__ out) {
  __shared__ float hb[64];
  int g = blockIdx.x, j = threadIdx.x;
  float c = fmaxf(pcnt[g], 1.f);
  float h = bc1[j];
  const float* pp = psum + g * 64;
  #pragma unroll
  for (int i4 = 0; i4 < 16; ++i4) {
    float4 pv = *(const float4*)(pp + i4 * 4);
    h += (pv.x / c) * wc1[(i4 * 4 + 0) * 64 + j] + (pv.y / c) * wc1[(i4 * 4 + 1) * 64 + j]
       + (pv.z / c) * wc1[(i4 * 4 + 2) * 64 + j] + (pv.w / c) * wc1[(i4 * 4 + 3) * 64 + j];
  }
  hb[j] = fmaxf(h, 0.f);
  __syncthreads();
  if (j < 4) {
    float o = bc2[j];
    #pragma unroll
    for (int k = 0; k < 64; ++k) o += hb[k] * wc2[k * 4 + j];
    out[g * 4 + j] = o;
  }
}

extern "C" void kernel_launch(void* const* d_in, const int* in_sizes, int n_in,
                              void* d_out, int out_size, void* d_ws, size_t ws_size,
                              hipStream_t stream) {
  const float* node_ids = (const float*)d_in[0];
  const int*   ei       = (const int*)d_in[1];
  const float* ea       = (const float*)d_in[2];
  const int*   batch    = (const int*)d_in[3];
  const float* w1_0 = (const float*)d_in[4];
  const float* b1_0 = (const float*)d_in[5];
  const float* w2_0 = (const float*)d_in[6];
  const float* b2_0 = (const float*)d_in[7];
  const float* root0 = (const float*)d_in[8];
  const float* bias0 = (const float*)d_in[9];
  const float* w1_1 = (const float*)d_in[10];
  const float* b1_1 = (const float*)d_in[11];
  const float* w2_1 = (const float*)d_in[12];
  const float* b2_1 = (const float*)d_in[13];
  const float* root1 = (const float*)d_in[14];
  const float* bias1 = (const float*)d_in[15];
  const float* wc1 = (const float*)d_in[16];
  const float* bc1 = (const float*)d_in[17];
  const float* wc2 = (const float*)d_in[18];
  const float* bc2 = (const float*)d_in[19];
  float* out = (float*)d_out;

  char* ws = (char*)d_ws;
  _Float16* BC = (_Float16*)ws;                        // 33,816,576 B (8*258*16384)
  unsigned int* WP = (unsigned int*)(ws + 33816576);   //     65,536 B (8*256*32)
  float* x1   = (float*)(ws + 33882112);               //  2,560,000 B
  float* agg0 = (float*)(ws + 36442112);               //  2,560,000 B (zeroed)
  float* agg1 = (float*)(ws + 39002112);               //  2,560,000 B (zeroed)
  float* cnt  = (float*)(ws + 41562112);               //     40,000 B (zeroed)
  float* psum = (float*)(ws + 41602112);               //     16,384 B (zeroed)
  float* pcnt = (float*)(ws + 41618496);               //        256 B (zeroed)
  float* P8   = (float*)(ws + 41618752);               // 82,313,216 B (fully overwritten)
  const size_t NEED_PART = 41618752ull + (size_t)8 * PSLICE * 4;

  (void)hipMemsetAsync(agg0, 0, 2560000 + 2560000 + 40000 + 16384 + 256, stream);

  prep_B<<<(8 * CPS * 128 + 255) / 256, 256, 0, stream>>>(w2_1, b2_1, BC);
  prep_W<<<8, 256, 0, stream>>>(w1_1, b1_1, WP);
  layer0_edge<<<512, 256, 0, stream>>>(node_ids, ei, ea, w1_0, b1_0, w2_0, b2_0, agg0, cnt);
  node0<<<(N_NODES * 64 + 255) / 256, 256, 0, stream>>>(node_ids, batch, agg0, cnt, root0, bias0, x1, pcnt);

  if (ws_size >= NEED_PART) {
    fused_edge_gemm<true><<<NTILES, 256, 0, stream>>>(ei, ea, x1, WP, BC, P8);
    reduce_partials<<<(N_EDGES * 64) / 256, 256, 0, stream>>>(P8, ei, agg1);
  } else {
    fused_edge_gemm<false><<<NTILES, 256, 0, stream>>>(ei, ea, x1, WP, BC, agg1);
  }

  node1_pool<<<(N_NODES + 3) / 4, 256, 0, stream>>>(batch, x1, agg1, cnt, root1, bias1, psum);
  classifier<<<N_GRAPH, 64, 0, stream>>>(psum, pcnt, wc1, bc1, wc2, bc2, out);
}

// Round 12
// 1168.013 us; speedup vs baseline: 1.2647x; 1.1520x over previous
//
#include <hip/hip_runtime.h>
#include <hip/hip_fp16.h>

#define N_NODES 10000
#define N_EDGES 40000
#define N_GRAPH 64
#define CPS     258             // chunks per slice: 256 real + bias(ks7)/pad + pad
#define NTILES  1256            // 157 edge-blocks * 8 K-slices
#define EPAD    40192           // 157 * 256 padded edge count
#define PSLICE  (EPAD * 64)     // floats per partial slice

typedef _Float16 half8_t  __attribute__((ext_vector_type(8)));
typedef float    floatx16 __attribute__((ext_vector_type(16)));

__device__ __forceinline__ void gload_lds16(const void* g, void* l) {
  __builtin_amdgcn_global_load_lds((const __attribute__((address_space(1))) void*)g,
                                   (__attribute__((address_space(3))) void*)l, 16, 0, 0);
}

// swizzle: 16B-slot permutation within each row's 256B chunk image (row bits 0-2)
__device__ __host__ __forceinline__ int swz(int row) {
  return ((row & 3) << 1) | ((row >> 2) & 1);
}

__device__ __forceinline__ half8_t splat8(_Float16 v) {
  half8_t r = {v, v, v, v, v, v, v, v};
  return r;
}

union U32H2 { unsigned int u; __half2 h2; };

// ---------------- prep v3: BC[ks][c][o][128], chunk-major pre-swizzled image.
// Thread per (ks, c, pos=logical kk within chunk); o-loop reads w2 row CONTIGUOUSLY
// (256 B/thread). [R11: cut non-fused time 365 -> ~95 us]
__global__ void prep_B(const float* __restrict__ w2, const float* __restrict__ b2,
                       _Float16* __restrict__ BC) {
  int tid = blockIdx.x * 256 + threadIdx.x;
  if (tid >= 8 * CPS * 128) return;
  int ks  = tid / (CPS * 128);
  int rem = tid - ks * (CPS * 128);
  int c   = rem >> 7;
  int pos = rem & 127;
  int sl = pos >> 3, j3 = pos & 7;
  _Float16* dstb = BC + ((size_t)(ks * CPS + c) * 64) * 128;
  bool pad = (c > 256) || (c == 256 && ks != 7);
  int kk_l = ks * 32768 + c * 128 + pos;
  int k = kk_l >> 6, i = kk_l & 63;
  if (pad || k > 4096) {
    #pragma unroll 8
    for (int o = 0; o < 64; ++o)
      dstb[o * 128 + ((sl ^ swz(o)) << 3) + j3] = (_Float16)0.f;
  } else if (k < 4096) {
    const float* src = w2 + (size_t)k * 4096 + i * 64;
    #pragma unroll 8
    for (int o = 0; o < 64; ++o)
      dstb[o * 128 + ((sl ^ swz(o)) << 3) + j3] = (_Float16)src[o];
  } else {                       // k == 4096: bias rank (ks7 c256 pos<64)
    const float* src = b2 + i * 64;
    #pragma unroll 8
    for (int o = 0; o < 64; ++o)
      dstb[o * 128 + ((sl ^ swz(o)) << 3) + j3] = (_Float16)src[o];
  }
}

// ---------------- prep W: WP[ks][c][8 u32] = {w1 pairs d0..d3, b1 pair, 0,0,0} as half2
__global__ void prep_W(const float* __restrict__ w1, const float* __restrict__ b1,
                       unsigned int* __restrict__ WP) {
  int tid = blockIdx.x * 256 + threadIdx.x;
  if (tid >= 8 * 256) return;
  int ks = tid >> 8, c = tid & 255;
  int kb = ks * 512 + 2 * c;
  unsigned int* dst = WP + (size_t)tid * 8;
  #pragma unroll
  for (int d = 0; d < 4; ++d) {
    float2 v = *(const float2*)(w1 + d * 4096 + kb);
    U32H2 u; u.h2 = __floats2half2_rn(v.x, v.y);
    dst[d] = u.u;
  }
  float2 bv = *(const float2*)(b1 + kb);
  U32H2 u; u.h2 = __floats2half2_rn(bv.x, bv.y);
  dst[4] = u.u; dst[5] = 0; dst[6] = 0; dst[7] = 0;
}

// ---------------- layer 0: per-edge MLP (in_dim=1) + scatter-sum + degree count
__global__ void layer0_edge(const float* __restrict__ node_ids,
                            const int* __restrict__ ei,
                            const float* __restrict__ ea,
                            const float* __restrict__ w1, const float* __restrict__ b1,
                            const float* __restrict__ w2, const float* __restrict__ b2,
                            float* __restrict__ agg0, float* __restrict__ cnt) {
  __shared__ float w1s[256], b1s[64], w2s[4096], b2s[64], zb[4][64];
  int t = threadIdx.x;
  for (int idx = t; idx < 4096; idx += 256) w2s[idx] = w2[idx];
  if (t < 256) w1s[t] = w1[t];
  if (t < 64) { b1s[t] = b1[t]; b2s[t] = b2[t]; }
  __syncthreads();
  int w = t >> 6, l = t & 63;
  int gw = blockIdx.x * 4 + w;
  int nw = gridDim.x * 4;
  for (int e = gw; e < N_EDGES; e += nw) {
    float a0 = ea[e * 4 + 0], a1 = ea[e * 4 + 1], a2 = ea[e * 4 + 2], a3 = ea[e * 4 + 3];
    float z = a0 * w1s[l] + a1 * w1s[64 + l] + a2 * w1s[128 + l] + a3 * w1s[192 + l] + b1s[l];
    zb[w][l] = fmaxf(z, 0.f);
    asm volatile("s_waitcnt lgkmcnt(0)" ::: "memory");
    __builtin_amdgcn_sched_barrier(0);
    float h = b2s[l];
    #pragma unroll
    for (int k = 0; k < 64; ++k) h += zb[w][k] * w2s[k * 64 + l];
    int src = ei[e], dst = ei[N_EDGES + e];
    float msg = node_ids[src] * h;
    atomicAdd(&agg0[dst * 64 + l], msg);
    if (l == 0) atomicAdd(&cnt[dst], 1.0f);
  }
}

// ---------------- node update 0: x1 = relu(agg0/cnt + node_ids*root0 + bias0); pool counts
__global__ void node0(const float* __restrict__ node_ids, const int* __restrict__ batch,
                      const float* __restrict__ agg0, const float* __restrict__ cnt,
                      const float* __restrict__ root0, const float* __restrict__ bias0,
                      float* __restrict__ x1, float* __restrict__ pcnt) {
  int gid = blockIdx.x * 256 + threadIdx.x;
  if (gid >= N_NODES * 64) return;
  int n = gid >> 6, o = gid & 63;
  float c = fmaxf(cnt[n], 1.f);
  float v = agg0[gid] / c + node_ids[n] * root0[o] + bias0[o];
  x1[gid] = fmaxf(v, 0.f);
  if (o == 0) atomicAdd(&pcnt[batch[n]], 1.0f);
}

// ---------------- layer 1 fused: msg[e,o] = sum_kk (z_e[k]*x_e[i]) * B'[kk,o]
// grid = 1256 (157 eb x 8 ks); block = 4 waves; wave = 64 edges x 64 o (m=2, n=2:
// one af feeds 2 MFMAs -- best measured geometry, R10 = 1026 us).
// 3-buffer LDS ring (48 KB), raw s_barrier + counted vmcnt(4).
template <bool PART>
__launch_bounds__(256, 3)
__global__ void fused_edge_gemm(const int* __restrict__ ei,
                                const float* __restrict__ ea,
                                const float* __restrict__ x1,
                                const unsigned int* __restrict__ WP,
                                const _Float16* __restrict__ BC,
                                float* __restrict__ outbuf) {
  __shared__ __attribute__((aligned(16))) _Float16 Bl[3][64 * 128]; // 49152 B
  int t = threadIdx.x;
  int ks = blockIdx.x & 7;
  int eb = blockIdx.x >> 3;
  int e0 = eb * 256;
  int w = t >> 6, l = t & 63;
  int half_ = l >> 5;
  int lane31 = l & 31;
  int swo = swz(lane31);             // same for lane31 and lane31+32 (row bits 0-2)

  // per-lane A data: 2 edge-tiles of 32; lane holds x[row=lane31][q*16+half_*8+0..7]
  half8_t xh8[2][4];
  __half2 eb_bc[2][4];
  #pragma unroll
  for (int m = 0; m < 2; ++m) {
    int e = e0 + w * 64 + m * 32 + lane31;
    if (e < N_EDGES) {
      int src = ei[e];
      const float* xp = x1 + src * 64 + half_ * 8;
      #pragma unroll
      for (int q = 0; q < 4; ++q) {
        float4 f0 = *(const float4*)(xp + q * 16);
        float4 f1 = *(const float4*)(xp + q * 16 + 4);
        half8_t v;
        v[0] = (_Float16)f0.x; v[1] = (_Float16)f0.y;
        v[2] = (_Float16)f0.z; v[3] = (_Float16)f0.w;
        v[4] = (_Float16)f1.x; v[5] = (_Float16)f1.y;
        v[6] = (_Float16)f1.z; v[7] = (_Float16)f1.w;
        xh8[m][q] = v;
      }
      float4 av = *(const float4*)(ea + e * 4);
      eb_bc[m][0] = __float2half2_rn(av.x); eb_bc[m][1] = __float2half2_rn(av.y);
      eb_bc[m][2] = __float2half2_rn(av.z); eb_bc[m][3] = __float2half2_rn(av.w);
    } else {
      #pragma unroll
      for (int q = 0; q < 4; ++q) xh8[m][q] = splat8((_Float16)0.f);
      #pragma unroll
      for (int d = 0; d < 4; ++d) eb_bc[m][d] = __float2half2_rn(0.f);
    }
  }

  floatx16 acc[2][2];
  #pragma unroll
  for (int m = 0; m < 2; ++m)
    #pragma unroll
    for (int n = 0; n < 2; ++n)
      #pragma unroll
      for (int r = 0; r < 16; ++r) acc[m][n][r] = 0.f;

  // addressing
  const char* gp = (const char*)BC + (size_t)ks * (CPS * 16384) + w * 4096 + l * 16;
  char*       sd = (char*)&Bl[0][0] + w * 4096 + l * 16;     // + buf*16384
  const char* rb = (const char*)&Bl[0][0] + lane31 * 256;    // + buf*16384
  const unsigned int* wp = WP + (size_t)ks * 256 * 8;        // uniform per block

  auto stg = [&](int sb) {           // stage next pending chunk into ring buffer sb
    char* d = sd + sb * 16384;
    gload_lds16(gp,        d);
    gload_lds16(gp + 1024, d + 1024);
    gload_lds16(gp + 2048, d + 2048);
    gload_lds16(gp + 3072, d + 3072);
    gp += 16384;
  };

  const __half zero1 = __float2half(0.f);
  union H2F { __half2 h2; _Float16 f[2]; };
  half8_t zs8[2][2];

  auto zgen = [&](int c) {           // z for chunk c's two real k values (uniform WP read)
    uint4 wv = *(const uint4*)(wp + c * 8);
    unsigned int bb = wp[c * 8 + 4];
    U32H2 uw0, uw1, uw2, uw3, ub;
    uw0.u = wv.x; uw1.u = wv.y; uw2.u = wv.z; uw3.u = wv.w; ub.u = bb;
    #pragma unroll
    for (int m = 0; m < 2; ++m) {
      __half2 h = __hfma2(eb_bc[m][0], uw0.h2, ub.h2);
      h = __hfma2(eb_bc[m][1], uw1.h2, h);
      h = __hfma2(eb_bc[m][2], uw2.h2, h);
      h = __hfma2(eb_bc[m][3], uw3.h2, h);
      H2F u; u.h2 = __halves2half2(__hmax(__low2half(h),  zero1),
                                   __hmax(__high2half(h), zero1));
      zs8[m][0] = splat8(u.f[0]);
      zs8[m][1] = splat8(u.f[1]);
    }
  };
  auto zbias = [&]() {               // c>=256: ks7 bias rank (z=1/0); pads have B=0
    #pragma unroll
    for (int m = 0; m < 2; ++m) {
      zs8[m][0] = splat8((_Float16)1.f);
      zs8[m][1] = splat8((_Float16)0.f);
    }
  };

  auto cmp = [&](int rbuf) {         // 32 MFMA on ring buffer rbuf
    const char* base = rb + rbuf * 16384;
    __builtin_amdgcn_s_setprio(1);
    #pragma unroll
    for (int t8 = 0; t8 < 8; ++t8) {
      int slot = (t8 * 2 + half_) ^ swo;
      const char* ba = base + slot * 16;
      half8_t bf0 = *(const half8_t*)ba;             // o rows 0..31
      half8_t bf1 = *(const half8_t*)(ba + 8192);    // o rows 32..63 (same swizzle)
      #pragma unroll
      for (int m = 0; m < 2; ++m) {
        half8_t af = xh8[m][t8 & 3] * zs8[m][t8 >> 2];
        acc[m][0] = __builtin_amdgcn_mfma_f32_32x32x16_f16(af, bf0, acc[m][0], 0, 0, 0);
        acc[m][1] = __builtin_amdgcn_mfma_f32_32x32x16_f16(af, bf1, acc[m][1], 0, 0, 0);
      }
    }
    __builtin_amdgcn_s_setprio(0);
  };

#define SYNC4 do { asm volatile("s_waitcnt vmcnt(4)" ::: "memory"); \
                   __builtin_amdgcn_sched_barrier(0); \
                   __builtin_amdgcn_s_barrier(); \
                   __builtin_amdgcn_sched_barrier(0); } while (0)
#define SYNC0 do { asm volatile("s_waitcnt vmcnt(0)" ::: "memory"); \
                   __builtin_amdgcn_sched_barrier(0); \
                   __builtin_amdgcn_s_barrier(); \
                   __builtin_amdgcn_sched_barrier(0); } while (0)

  // ring prologue: chunks 0,1 in flight
  stg(0); stg(1);

  // phase c: zgen(c); vmcnt(4) certifies chunk c landed (FIFO); barrier; stage c+2
  // (all waves are past reading that buffer); 32 MFMAs on buf c%3.
  int c = 0;
  for (int it = 0; it < 85; ++it) {  // c = 0..254
    zgen(c);     SYNC4; stg(2); cmp(0);
    zgen(c + 1); SYNC4; stg(0); cmp(1);
    zgen(c + 2); SYNC4; stg(1); cmp(2);
    c += 3;
  }
  // tail: c = 255 (stages chunk 257), 256 (bias/pad), 257 (pad)
  zgen(255); SYNC4; stg(2); cmp(0);
  zbias();   SYNC4;         cmp(1);
  zbias();   SYNC0;         cmp(2);

#undef SYNC4
#undef SYNC0

  // epilogue: 32x32 C/D layout: col=lane&31, row=(reg&3)+8*(reg>>2)+4*(lane>>5)
  if (PART) {
    float* pb = outbuf + ((size_t)ks * EPAD + e0 + w * 64) * 64 + lane31;
    #pragma unroll
    for (int m = 0; m < 2; ++m) {
      #pragma unroll
      for (int r = 0; r < 16; ++r) {
        int row = m * 32 + (r & 3) + 8 * (r >> 2) + 4 * half_;
        pb[(size_t)row * 64]      = acc[m][0][r];
        pb[(size_t)row * 64 + 32] = acc[m][1][r];
      }
    }
  } else {
    #pragma unroll
    for (int m = 0; m < 2; ++m) {
      #pragma unroll
      for (int r = 0; r < 16; ++r) {
        int e = e0 + w * 64 + m * 32 + (r & 3) + 8 * (r >> 2) + 4 * half_;
        if (e < N_EDGES) {
          int dst = ei[N_EDGES + e];
          atomicAdd(&outbuf[dst * 64 + lane31],      acc[m][0][r]);
          atomicAdd(&outbuf[dst * 64 + lane31 + 32], acc[m][1][r]);
        }
      }
    }
  }
}

// ---------------- reduce 8 partial slices -> scatter into agg1 (8x fewer atomics)
__global__ void reduce_partials(const float* __restrict__ P8, const int* __restrict__ ei,
                                float* __restrict__ agg1) {
  int gid = blockIdx.x * 256 + threadIdx.x;
  if (gid >= N_EDGES * 64) return;
  int e = gid >> 6;
  float s = 0.f;
  #pragma unroll
  for (int ks = 0; ks < 8; ++ks) s += P8[(size_t)ks * PSLICE + gid];
  int dst = ei[N_EDGES + e];
  atomicAdd(&agg1[dst * 64 + (gid & 63)], s);
}

// ---------------- node update 1 + global mean pool accumulate
__global__ void node1_pool(const int* __restrict__ batch, const float* __restrict__ x1,
                           const float* __restrict__ agg1, const float* __restrict__ cnt,
                           const float* __restrict__ root1, const float* __restrict__ bias1,
                           float* __restrict__ psum) {
  __shared__ float rt[4096];
  int t = threadIdx.x;
  for (int idx = t; idx < 4096; idx += 256) rt[idx] = root1[idx];
  __syncthreads();
  int w = t >> 6, l = t & 63;
  int n = blockIdx.x * 4 + w;
  if (n >= N_NODES) return;
  float c = fmaxf(cnt[n], 1.f);
  float acc = agg1[n * 64 + l] / c + bias1[l];
  const float* xp = x1 + n * 64;
  #pragma unroll
  for (int i4 = 0; i4 < 16; ++i4) {
    float4 xv = *(const float4*)(xp + i4 * 4);
    acc += xv.x * rt[(i4 * 4 + 0) * 64 + l] + xv.y * rt[(i4 * 4 + 1) * 64 + l]
         + xv.z * rt[(i4 * 4 + 2) * 64 + l] + xv.w * rt[(i4 * 4 + 3) * 64 + l];
  }
  acc = fmaxf(acc, 0.f);
  atomicAdd(&psum[batch[n] * 64 + l], acc);
}

// ---------------- classifier head: one wave per graph
__global__ void classifier(const float* __restrict__ psum, const float* __restrict__ pcnt,
                           const float* __restrict__ wc1, const float* __restrict__ bc1,
                           const float* __restrict__ wc2, const float* __restrict__ bc2,
                           float* __restrict__ out) {
  __shared__ float hb[64];
  int g = blockIdx.x, j = threadIdx.x;
  float c = fmaxf(pcnt[g], 1.f);
  float h = bc1[j];
  const float* pp = psum + g * 64;
  #pragma unroll
  for (int i4 = 0; i4 < 16; ++i4) {
    float4 pv = *(const float4*)(pp + i4 * 4);
    h += (pv.x / c) * wc1[(i4 * 4 + 0) * 64 + j] + (pv.y / c) * wc1[(i4 * 4 + 1) * 64 + j]
       + (pv.z / c) * wc1[(i4 * 4 + 2) * 64 + j] + (pv.w / c) * wc1[(i4 * 4 + 3) * 64 + j];
  }
  hb[j] = fmaxf(h, 0.f);
  __syncthreads();
  if (j < 4) {
    float o = bc2[j];
    #pragma unroll
    for (int k = 0; k < 64; ++k) o += hb[k] * wc2[k * 4 + j];
    out[g * 4 + j] = o;
  }
}

extern "C" void kernel_launch(void* const* d_in, const int* in_sizes, int n_in,
                              void* d_out, int out_size, void* d_ws, size_t ws_size,
                              hipStream_t stream) {
  const float* node_ids = (const float*)d_in[0];
  const int*   ei       = (const int*)d_in[1];
  const float* ea       = (const float*)d_in[2];
  const int*   batch    = (const int*)d_in[3];
  const float* w1_0 = (const float*)d_in[4];
  const float* b1_0 = (const float*)d_in[5];
  const float* w2_0 = (const float*)d_in[6];
  const float* b2_0 = (const float*)d_in[7];
  const float* root0 = (const float*)d_in[8];
  const float* bias0 = (const float*)d_in[9];
  const float* w1_1 = (const float*)d_in[10];
  const float* b1_1 = (const float*)d_in[11];
  const float* w2_1 = (const float*)d_in[12];
  const float* b2_1 = (const float*)d_in[13];
  const float* root1 = (const float*)d_in[14];
  const float* bias1 = (const float*)d_in[15];
  const float* wc1 = (const float*)d_in[16];
  const float* bc1 = (const float*)d_in[17];
  const float* wc2 = (const float*)d_in[18];
  const float* bc2 = (const float*)d_in[19];
  float* out = (float*)d_out;

  char* ws = (char*)d_ws;
  _Float16* BC = (_Float16*)ws;                        // 33,816,576 B (8*258*16384)
  unsigned int* WP = (unsigned int*)(ws + 33816576);   //     65,536 B (8*256*32)
  float* x1   = (float*)(ws + 33882112);               //  2,560,000 B
  float* agg0 = (float*)(ws + 36442112);               //  2,560,000 B (zeroed)
  float* agg1 = (float*)(ws + 39002112);               //  2,560,000 B (zeroed)
  float* cnt  = (float*)(ws + 41562112);               //     40,000 B (zeroed)
  float* psum = (float*)(ws + 41602112);               //     16,384 B (zeroed)
  float* pcnt = (float*)(ws + 41618496);               //        256 B (zeroed)
  float* P8   = (float*)(ws + 41618752);               // 82,313,216 B (fully overwritten)
  const size_t NEED_PART = 41618752ull + (size_t)8 * PSLICE * 4;

  (void)hipMemsetAsync(agg0, 0, 2560000 + 2560000 + 40000 + 16384 + 256, stream);

  prep_B<<<(8 * CPS * 128 + 255) / 256, 256, 0, stream>>>(w2_1, b2_1, BC);
  prep_W<<<8, 256, 0, stream>>>(w1_1, b1_1, WP);
  layer0_edge<<<512, 256, 0, stream>>>(node_ids, ei, ea, w1_0, b1_0, w2_0, b2_0, agg0, cnt);
  node0<<<(N_NODES * 64 + 255) / 256, 256, 0, stream>>>(node_ids, batch, agg0, cnt, root0, bias0, x1, pcnt);

  if (ws_size >= NEED_PART) {
    fused_edge_gemm<true><<<NTILES, 256, 0, stream>>>(ei, ea, x1, WP, BC, P8);
    reduce_partials<<<(N_EDGES * 64) / 256, 256, 0, stream>>>(P8, ei, agg1);
  } else {
    fused_edge_gemm<false><<<NTILES, 256, 0, stream>>>(ei, ea, x1, WP, BC, agg1);
  }

  node1_pool<<<(N_NODES + 3) / 4, 256, 0, stream>>>(batch, x1, agg1, cnt, root1, bias1, psum);
  classifier<<<N_GRAPH, 64, 0, stream>>>(psum, pcnt, wc1, bc1, wc2, bc2, out);
}